// Round 9
// baseline (228.975 us; speedup 1.0000x reference)
//
#include <hip/hip_runtime.h>
#include <hip/hip_bf16.h>

// Problem: B=4, Tq=Tk=2048, E=1024, D=128, d=64. All inputs fp32, output fp32.
// Round 19: T14 retry on the r18 base. r18 post-mortem: occupancy 17.7->31.1%
// (VGPR 52) but dur flat at 44us -> wall is the per-tile barrier-paced chain
// (stage load -> drain -> ds_write -> barrier -> compute), not TLP. T14
// (issue next tile's loads to regs before compute; write after the post-
// compute barrier) failed in r12-r14 only from the 128-VGPR cliff at 256 thr;
// at 512 thr the staged tile is 4xint4 = 16 VGPR on a 52-VGPR base -> free.
// Only attn_split changes vs r18 (loadregs/writeregs split); everything else
// identical. gemm_proj / cvtWT(+lam) / combine / tripwire unchanged.

#define TQ 2048
#define TK 2048
#define EMB 1024
#define HD 128
#define MQ 8192  // B*Tq rows

typedef __attribute__((ext_vector_type(8))) short short8;   // 8 bf16 = 4 VGPR
typedef __attribute__((ext_vector_type(4))) float floatx4;  // MFMA acc

__device__ __forceinline__ unsigned short f2bf(float f) {  // RNE fp32->bf16
  union { float f; unsigned u; } v; v.f = f;
  unsigned r = v.u + 0x7fffu + ((v.u >> 16) & 1u);
  return (unsigned short)(r >> 16);
}
__device__ __forceinline__ float bf2f(unsigned short s) {
  union { unsigned u; float f; } v; v.u = ((unsigned)s) << 16;
  return v.f;
}

typedef const __attribute__((address_space(1))) unsigned int guint;
typedef __attribute__((address_space(3))) unsigned int luint;
__device__ __forceinline__ void gl16(const void* g, void* l) {
  __builtin_amdgcn_global_load_lds((guint*)g, (luint*)l, 16, 0, 0);
}

// ------------------------------------- weight convert+transpose (+ lambda) ----
__global__ __launch_bounds__(256) void cvtWT_kernel(
    const float* __restrict__ Wq, const float* __restrict__ Wk,
    const float* __restrict__ Wv, unsigned short* __restrict__ WqT,
    unsigned short* __restrict__ WkT, unsigned short* __restrict__ WvT,
    const float* __restrict__ lq1, const float* __restrict__ lk1,
    const float* __restrict__ lq2, const float* __restrict__ lk2,
    const float* __restrict__ linit, float* __restrict__ lam_out) {
  const int g = blockIdx.y;
  if (g == 3) {  // lambda: one block, first wave
    if (blockIdx.x == 0 && threadIdx.x < 64) {
      int j = threadIdx.x;
      float s1 = lq1[j] * lk1[j] + lq1[j + 64] * lk1[j + 64];
      float s2 = lq2[j] * lk2[j] + lq2[j + 64] * lk2[j + 64];
      for (int off = 1; off < 64; off <<= 1) {
        s1 += __shfl_xor(s1, off);
        s2 += __shfl_xor(s2, off);
      }
      if (j == 0) lam_out[0] = __expf(s1) - __expf(s2) + linit[0];
    }
    return;
  }
  const float* W = (g == 0) ? Wq : (g == 1) ? Wk : Wv;
  unsigned short* WT = (g == 0) ? WqT : (g == 1) ? WkT : WvT;
  int idx = blockIdx.x * 256 + threadIdx.x;  // [0, 131072)
  int n = idx >> 10, k = idx & 1023;
  WT[idx] = f2bf(W[(size_t)k * HD + n]);
}

// -------------------------------------------------------- MFMA projections ----
// grid (MQ/32, 3), 256 thr (4 waves). wave w: wm=w&1 -> rows 16wm..+16,
// wn=w>>1 -> cols 64wn..+64. Per K-step (BK=64): A fp32 32x64 (8KB, 8 chunks)
// + B^T bf16 128x64 (16KB, 16 chunks) staged via global_load_lds dwordx4,
// double-buffered; 8 MFMA/wave. g=0: qb*(0.125); g=1: kb; g=2: vbT^T.
__global__ __launch_bounds__(256) void gemm_proj_kernel(
    const float* __restrict__ x, const float* __restrict__ enc,
    const unsigned short* __restrict__ WqT, const unsigned short* __restrict__ WkT,
    const unsigned short* __restrict__ WvT,
    const float* __restrict__ bq, const float* __restrict__ bk,
    const float* __restrict__ bv,
    unsigned short* __restrict__ qb, unsigned short* __restrict__ kb,
    unsigned short* __restrict__ vbT) {
  __shared__ __align__(16) float Ab[2][32 * 64];             // 16 KB, linear (no pad)
  __shared__ __align__(16) unsigned short Bb[2][128 * 64];   // 32 KB, linear (no pad)
  const int t = threadIdx.x;
  const int w = t >> 6, lane = t & 63;
  const int lo = lane & 15, quad = lane >> 4;
  const int wm = w & 1, wn = w >> 1;
  const int g = blockIdx.y;
  const size_t m0 = (size_t)blockIdx.x * 32;
  const float* A = (g == 0) ? x : enc;
  const unsigned short* BT = (g == 0) ? WqT : (g == 1) ? WkT : WvT;
  const float* bias = (g == 0) ? bq : (g == 1) ? bk : bv;

  // Per-lane staging sources, pre-swizzled so linear LDS + swizzled ds_read
  // reconstructs the original element (involution: col_byte ^= ((row&7)<<4)).
  // A: 8 chunks of 1KB (4 rows x 256B); wave w owns chunks 2w, 2w+1.
  const float* gA[2];
  int ldsAoff[2];
#pragma unroll
  for (int j = 0; j < 2; ++j) {
    int c = 2 * w + j;
    int row = 4 * c + (lane >> 4);
    int colb = ((lane & 15) * 16) ^ ((row & 7) << 4);
    gA[j] = A + (m0 + row) * EMB + (colb >> 2);
    ldsAoff[j] = c * 1024;
  }
  // B: 16 chunks of 1KB (8 rows x 128B); wave w owns chunks 4w..4w+3.
  const unsigned short* gB[4];
  int ldsBoff[4];
#pragma unroll
  for (int j = 0; j < 4; ++j) {
    int c = 4 * w + j;
    int row = 8 * c + (lane >> 3);
    int colb = ((lane & 7) * 16) ^ ((row & 7) << 4);
    gB[j] = BT + (size_t)row * EMB + (colb >> 1);
    ldsBoff[j] = c * 1024;
  }

  floatx4 acc[4];
  const floatx4 zz = {0.f, 0.f, 0.f, 0.f};
#pragma unroll
  for (int i = 0; i < 4; ++i) acc[i] = zz;

  const int xr = (lo & 7) << 4;

  auto stage = [&](int kt, int bsel) {
#pragma unroll
    for (int j = 0; j < 2; ++j) gl16(gA[j] + kt, (char*)&Ab[bsel][0] + ldsAoff[j]);
#pragma unroll
    for (int j = 0; j < 4; ++j) gl16(gB[j] + kt, (char*)&Bb[bsel][0] + ldsBoff[j]);
  };

  auto compute = [&](int bsel) {
    const char* Arow = (const char*)&Ab[bsel][(16 * wm + lo) * 64];
    const char* Bbase = (const char*)&Bb[bsel][0];
#pragma unroll
    for (int ks = 0; ks < 2; ++ks) {
      int a0 = (ks * 128 + quad * 32) ^ xr;
      float4 fa = *(const float4*)(Arow + a0);         // orig cols ks*32+q8 .. +3
      float4 fb = *(const float4*)(Arow + (a0 ^ 16));  // orig cols ks*32+q8+4 .. +7
      short8 af;
      af[0] = (short)f2bf(fa.x); af[1] = (short)f2bf(fa.y);
      af[2] = (short)f2bf(fa.z); af[3] = (short)f2bf(fa.w);
      af[4] = (short)f2bf(fb.x); af[5] = (short)f2bf(fb.y);
      af[6] = (short)f2bf(fb.z); af[7] = (short)f2bf(fb.w);
      int b0 = (ks * 64 + quad * 16) ^ xr;
#pragma unroll
      for (int nt = 0; nt < 4; ++nt) {
        int row = wn * 64 + nt * 16 + lo;
        short8 bfr = *(const short8*)(Bbase + row * 128 + b0);
        acc[nt] = __builtin_amdgcn_mfma_f32_16x16x32_bf16(af, bfr, acc[nt], 0, 0, 0);
      }
    }
  };

  // prologue: stage K-tile 0 into buf0 (syncthreads drains vmcnt+lgkmcnt)
  stage(0, 0);
  __syncthreads();

  // 2-phase pipeline, unrolled 2-deep -> static buffer indices
  for (int kt = 0; kt < EMB; kt += 128) {
    stage(kt + 64, 1);          // prefetch next tile (kt+64 <= 960, always valid)
    compute(0);                 // consume tile kt
    __syncthreads();            // drains: buf1 loads done, buf0 reads done
    if (kt + 128 < EMB) stage(kt + 128, 0);
    compute(1);                 // consume tile kt+64
    __syncthreads();
  }

  // epilogue: rows m0+16wm+quad*4+r, cols 64wn+nt*16+lo
  const int mrow = 16 * wm + quad * 4;
  if (g < 2) {
    unsigned short* Y = (g == 0) ? qb : kb;
    const float sc = (g == 0) ? 0.125f : 1.0f;
#pragma unroll
    for (int nt = 0; nt < 4; ++nt) {
      float bn = bias[wn * 64 + nt * 16 + lo];
#pragma unroll
      for (int r = 0; r < 4; ++r)
        Y[(m0 + mrow + r) * HD + wn * 64 + nt * 16 + lo] = f2bf((acc[nt][r] + bn) * sc);
    }
  } else {
#pragma unroll
    for (int nt = 0; nt < 4; ++nt) {
      float bn = bias[wn * 64 + nt * 16 + lo];
      unsigned long long pk = 0;
#pragma unroll
      for (int r = 0; r < 4; ++r)
        pk |= (unsigned long long)f2bf(acc[nt][r] + bn) << (16 * r);
      *(unsigned long long*)&vbT[(size_t)(wn * 64 + nt * 16 + lo) * MQ + m0 + mrow] = pk;
    }
  }
}

// ---------------------------------------------------- attention (key-split) ----
// Round 19: r18 group-split (512 thr, 8 waves, VGPR 52) + T14 async staging:
// issue tile t+1's 4 int4 loads into regs before compute (latency hides under
// QK+softmax+PV), drain+ds_write after the post-compute barrier. +16 VGPR.
__global__ __launch_bounds__(512, 4) void attn_split_kernel(
    const unsigned short* __restrict__ qb, const unsigned short* __restrict__ kb,
    const unsigned short* __restrict__ vbT,
    unsigned short* __restrict__ pO1, unsigned short* __restrict__ pO2,
    float2* __restrict__ pstats, int nkeys) {
  __shared__ __align__(16) unsigned short Kls[64][136];   // 17.4 KB
  __shared__ __align__(16) unsigned short Vt[128][72];    // 18.4 KB
  __shared__ __align__(16) unsigned short Pls[8][16][72]; // 18.4 KB

  const int t = threadIdx.x;
  const int w = t >> 6;        // 0..7
  const int g = w >> 2;        // softmax group 0/1
  const int wv = w & 3;        // wave within group -> q-row block
  const int lane = t & 63;
  const int lo = lane & 15;
  const int quad = lane >> 4;
  const int q8 = quad * 8;
  const int b = blockIdx.y;
  const int q0 = blockIdx.x * 64;
  const int ksp = blockIdx.z;
  const int kt0 = ksp * nkeys;
  const int ksTot = TK / nkeys;
  const size_t kbase = (size_t)b * TK;

  const size_t qrow = (size_t)b * TQ + q0 + wv * 16 + lo;
  short8 qf[2];
#pragma unroll
  for (int ks = 0; ks < 2; ++ks)
    qf[ks] = *(const short8*)&qb[qrow * HD + g * 64 + ks * 32 + q8];

  floatx4 o[8];
  const floatx4 zz = {0.f, 0.f, 0.f, 0.f};
#pragma unroll
  for (int i = 0; i < 8; ++i) o[i] = zz;
  float m[4], l[4];
#pragma unroll
  for (int r = 0; r < 4; ++r) { m[r] = -1e30f; l[r] = 0.f; }

  // T14 staging registers: 2 K-chunks + 2 V-chunks per thread (16 VGPR)
  int4 kreg[2], vreg[2];
  auto loadregs = [&](int kt) {
#pragma unroll
    for (int i = 0; i < 2; ++i) {
      int c = t + 512 * i;
      int key = c >> 4, f0 = (c & 15) * 8;
      kreg[i] = *(const int4*)&kb[(kbase + kt + key) * HD + f0];
      int f = c >> 3, k0 = (c & 7) * 8;
      vreg[i] = *(const int4*)&vbT[(size_t)f * MQ + kbase + kt + k0];
    }
  };
  auto writeregs = [&]() {
#pragma unroll
    for (int i = 0; i < 2; ++i) {
      int c = t + 512 * i;
      int key = c >> 4, f0 = (c & 15) * 8;
      *(int4*)&Kls[key][f0] = kreg[i];
      int f = c >> 3, k0 = (c & 7) * 8;
      *(int4*)&Vt[f][k0] = vreg[i];
    }
  };

  // prologue: tile 0 staged synchronously
  loadregs(kt0);
  writeregs();
  __syncthreads();

  for (int kt = kt0; kt < kt0 + nkeys; kt += 64) {
    const bool more = (kt + 64 < kt0 + nkeys);  // block-uniform
    if (more) loadregs(kt + 64);  // issue early: latency hides under compute

    floatx4 s[4];
#pragma unroll
    for (int i = 0; i < 4; ++i) s[i] = zz;
#pragma unroll
    for (int ks = 0; ks < 2; ++ks)
#pragma unroll
      for (int nt = 0; nt < 4; ++nt) {
        short8 kf = *(const short8*)&Kls[nt * 16 + lo][g * 64 + ks * 32 + q8];
        s[nt] = __builtin_amdgcn_mfma_f32_16x16x32_bf16(qf[ks], kf, s[nt], 0, 0, 0);
      }

    // per-row tile maxes (uniform within 16-lane groups after reduce)
    float tm[4];
#pragma unroll
    for (int r = 0; r < 4; ++r) {
      float a = fmaxf(fmaxf(s[0][r], s[1][r]), fmaxf(s[2][r], s[3][r]));
#pragma unroll
      for (int oo = 1; oo < 16; oo <<= 1) a = fmaxf(a, __shfl_xor(a, oo));
      tm[r] = a;
    }
    // T13 defer-max: rescale only when some row grew by >5 (wave-uniform)
    bool grow = false;
#pragma unroll
    for (int r = 0; r < 4; ++r) grow = grow || (tm[r] > m[r] + 5.f);
    if (__any(grow)) {
#pragma unroll
      for (int r = 0; r < 4; ++r) {
        float mn = fmaxf(m[r], tm[r]);
        float al = __expf(m[r] - mn);
        m[r] = mn;
        l[r] *= al;
#pragma unroll
        for (int nt = 0; nt < 8; ++nt) o[nt][r] *= al;
      }
    }
#pragma unroll
    for (int r = 0; r < 4; ++r) {
      float ls = 0.f;
#pragma unroll
      for (int nt = 0; nt < 4; ++nt) {
        float p = __expf(s[nt][r] - m[r]);
        ls += p;
        Pls[w][quad * 4 + r][nt * 16 + lo] = f2bf(p);
      }
#pragma unroll
      for (int oo = 1; oo < 16; oo <<= 1) ls += __shfl_xor(ls, oo);
      l[r] += ls;
    }

#pragma unroll
    for (int ks = 0; ks < 2; ++ks) {
      short8 p8 = *(const short8*)&Pls[w][lo][ks * 32 + q8];
#pragma unroll
      for (int nt = 0; nt < 8; ++nt) {
        short8 vf = *(const short8*)&Vt[nt * 16 + lo][ks * 32 + q8];
        o[nt] = __builtin_amdgcn_mfma_f32_16x16x32_bf16(p8, vf, o[nt], 0, 0, 0);
      }
    }

    if (more) {           // write-late: K/V/P reads above are done after barrier
      __syncthreads();
      writeregs();
    }
    __syncthreads();
  }

  unsigned short* Y = g ? pO2 : pO1;
#pragma unroll
  for (int r = 0; r < 4; ++r) {
    int rowb = q0 + wv * 16 + quad * 4 + r;
    size_t idx = ((size_t)(ksp * 4 + b)) * TQ + rowb;
    if (lo == 0)
      pstats[((size_t)(g * ksTot + ksp) * 4 + b) * TQ + rowb] = make_float2(m[r], l[r]);
#pragma unroll
    for (int nt = 0; nt < 8; ++nt)
      Y[idx * HD + nt * 16 + lo] = f2bf(o[nt][r]);
  }
}

// ---------------------------------------------------------------- combine ----
// pstats layout: [(g*ksn + s)*4 + b)*TQ + row] -> (m, l) per group.
__global__ __launch_bounds__(256) void attn_combine_kernel(
    const unsigned short* __restrict__ pO1, const unsigned short* __restrict__ pO2,
    const float2* __restrict__ pstats, const float* __restrict__ lam_ptr,
    float* __restrict__ out, int ksn) {
  const int t = threadIdx.x;
  const int b = blockIdx.y;
  const int row = blockIdx.x * 16 + (t >> 4);
  const int dg = t & 15;

  float m1s[8], l1s[8], m2s[8], l2s[8];
  float M1 = -1e30f, M2 = -1e30f;
  for (int s = 0; s < ksn; ++s) {
    float2 fa = pstats[((size_t)(s) * 4 + b) * TQ + row];
    float2 fb = pstats[((size_t)(ksn + s) * 4 + b) * TQ + row];
    m1s[s] = fa.x; l1s[s] = fa.y; m2s[s] = fb.x; l2s[s] = fb.y;
    M1 = fmaxf(M1, fa.x); M2 = fmaxf(M2, fb.x);
  }
  float L1 = 0.f, L2 = 0.f, e1[8], e2[8];
  for (int s = 0; s < ksn; ++s) {
    e1[s] = __expf(m1s[s] - M1); e2[s] = __expf(m2s[s] - M2);
    L1 += l1s[s] * e1[s]; L2 += l2s[s] * e2[s];
  }
  float a1[8], a2[8];
#pragma unroll
  for (int j = 0; j < 8; ++j) { a1[j] = 0.f; a2[j] = 0.f; }
  for (int s = 0; s < ksn; ++s) {
    size_t base = (((size_t)(s * 4 + b)) * TQ + row) * HD + dg * 8;
    int4 r1 = *(const int4*)&pO1[base];
    int4 r2 = *(const int4*)&pO2[base];
    const unsigned short* u1 = (const unsigned short*)&r1;
    const unsigned short* u2 = (const unsigned short*)&r2;
#pragma unroll
    for (int j = 0; j < 8; ++j) {
      a1[j] += bf2f(u1[j]) * e1[s];
      a2[j] += bf2f(u2[j]) * e2[s];
    }
  }
  const float i1 = 1.f / L1;
  const float i2 = lam_ptr[0] / L2;
  float4* op = (float4*)&out[((size_t)b * TQ + row) * HD + dg * 8];
  op[0] = make_float4(a1[0] * i1 - a2[0] * i2, a1[1] * i1 - a2[1] * i2,
                      a1[2] * i1 - a2[2] * i2, a1[3] * i1 - a2[3] * i2);
  op[1] = make_float4(a1[4] * i1 - a2[4] * i2, a1[5] * i1 - a2[5] * i2,
                      a1[6] * i1 - a2[6] * i2, a1[7] * i1 - a2[7] * i2);
}

// --------------------------------------------------------------- tripwire ----
__global__ __launch_bounds__(256) void attn_check_kernel(
    const unsigned short* __restrict__ qb, const unsigned short* __restrict__ kb,
    const unsigned short* __restrict__ vbT, const float* __restrict__ lamp,
    float* __restrict__ out) {
  __shared__ float qsh[HD];
  __shared__ float sred[4][4];
  const int t = threadIdx.x;
  const int w = t >> 6, lane = t & 63;
  const int bb = blockIdx.x & 3;
  const int q = (int)((blockIdx.x * 997u + 13u) & 2047u);
  const int dc = (int)((blockIdx.x * 37u + 5u) & 127u);

  const unsigned short* qr = &qb[((size_t)bb * TQ + q) * HD];
  if (t < HD) qsh[t] = bf2f(qr[t]);
  __syncthreads();

  float mx1 = -1e30f, mx2 = -1e30f;
  for (int it = 0; it < 8; ++it) {
    int key = t + 256 * it;
    const unsigned* kr = (const unsigned*)&kb[((size_t)bb * TK + key) * HD];
    float s1 = 0.f, s2 = 0.f;
#pragma unroll 8
    for (int du = 0; du < 32; ++du) {
      unsigned u1 = kr[du], u2 = kr[32 + du];
      s1 += qsh[2 * du] * bf2f((unsigned short)u1) +
            qsh[2 * du + 1] * bf2f((unsigned short)(u1 >> 16));
      s2 += qsh[64 + 2 * du] * bf2f((unsigned short)u2) +
            qsh[64 + 2 * du + 1] * bf2f((unsigned short)(u2 >> 16));
    }
    mx1 = fmaxf(mx1, s1); mx2 = fmaxf(mx2, s2);
  }
  for (int o = 1; o < 64; o <<= 1) {
    mx1 = fmaxf(mx1, __shfl_xor(mx1, o));
    mx2 = fmaxf(mx2, __shfl_xor(mx2, o));
  }
  if (lane == 0) { sred[0][w] = mx1; sred[1][w] = mx2; }
  __syncthreads();
  mx1 = fmaxf(fmaxf(sred[0][0], sred[0][1]), fmaxf(sred[0][2], sred[0][3]));
  mx2 = fmaxf(fmaxf(sred[1][0], sred[1][1]), fmaxf(sred[1][2], sred[1][3]));
  __syncthreads();

  float l1 = 0.f, l2 = 0.f, o1 = 0.f, o2 = 0.f;
  for (int it = 0; it < 8; ++it) {
    int key = t + 256 * it;
    const unsigned* kr = (const unsigned*)&kb[((size_t)bb * TK + key) * HD];
    float s1 = 0.f, s2 = 0.f;
#pragma unroll 8
    for (int du = 0; du < 32; ++du) {
      unsigned u1 = kr[du], u2 = kr[32 + du];
      s1 += qsh[2 * du] * bf2f((unsigned short)u1) +
            qsh[2 * du + 1] * bf2f((unsigned short)(u1 >> 16));
      s2 += qsh[64 + 2 * du] * bf2f((unsigned short)u2) +
            qsh[64 + 2 * du + 1] * bf2f((unsigned short)(u2 >> 16));
    }
    float p1 = __expf(s1 - mx1), p2 = __expf(s2 - mx2);
    float v = bf2f(vbT[(size_t)dc * MQ + bb * TK + key]);
    l1 += p1; l2 += p2; o1 += p1 * v; o2 += p2 * v;
  }
  for (int o = 1; o < 64; o <<= 1) {
    l1 += __shfl_xor(l1, o); l2 += __shfl_xor(l2, o);
    o1 += __shfl_xor(o1, o); o2 += __shfl_xor(o2, o);
  }
  if (lane == 0) { sred[0][w] = l1; sred[1][w] = l2; sred[2][w] = o1; sred[3][w] = o2; }
  __syncthreads();
  if (t == 0) {
    l1 = sred[0][0] + sred[0][1] + sred[0][2] + sred[0][3];
    l2 = sred[1][0] + sred[1][1] + sred[1][2] + sred[1][3];
    o1 = sred[2][0] + sred[2][1] + sred[2][2] + sred[2][3];
    o2 = sred[3][0] + sred[3][1] + sred[3][2] + sred[3][3];
    float res = o1 / l1 - lamp[0] * (o2 / l2);
    float got = out[((size_t)bb * TQ + q) * HD + dc];
    if (!(fabsf(res - got) <= 0.02f)) out[0] = 1.0e7f;
  }
}

extern "C" void kernel_launch(void* const* d_in, const int* in_sizes, int n_in,
                              void* d_out, int out_size, void* d_ws, size_t ws_size,
                              hipStream_t stream) {
  const float* x    = (const float*)d_in[0];
  const float* enc  = (const float*)d_in[1];
  const float* Wq   = (const float*)d_in[2];
  const float* bq   = (const float*)d_in[3];
  const float* Wk   = (const float*)d_in[4];
  const float* bk   = (const float*)d_in[5];
  const float* Wv   = (const float*)d_in[6];
  const float* bv   = (const float*)d_in[7];
  const float* lq1  = (const float*)d_in[8];
  const float* lk1  = (const float*)d_in[9];
  const float* lq2  = (const float*)d_in[10];
  const float* lk2  = (const float*)d_in[11];
  const float* lini = (const float*)d_in[12];
  float* out = (float*)d_out;

  char* p = (char*)d_ws;
  float* lam = (float*)p;                       p += 256;
  unsigned short* qb  = (unsigned short*)p;     p += (size_t)MQ * HD * 2;
  unsigned short* kb  = (unsigned short*)p;     p += (size_t)MQ * HD * 2;
  unsigned short* vbT = (unsigned short*)p;     p += (size_t)MQ * HD * 2;  // [128][8192]
  unsigned short* WqT = (unsigned short*)p;     p += (size_t)EMB * HD * 2;
  unsigned short* WkT = (unsigned short*)p;     p += (size_t)EMB * HD * 2;
  unsigned short* WvT = (unsigned short*)p;     p += (size_t)EMB * HD * 2;
  const size_t base_need = (size_t)(p - (char*)d_ws);

  // per-KS: stats 2 groups x 4 x TQ x sizeof(float2) (= 4*TQ*16) + pO1/pO2
  const size_t per_ks = (size_t)4 * TQ * 16 + 2ull * 4 * TQ * HD * 2;
  int KS = 4;
  while (KS > 1 && base_need + (size_t)KS * per_ks > ws_size) KS >>= 1;

  float2* pstats = (float2*)p;                  p += (size_t)KS * 4 * TQ * 16;
  unsigned short* pO1 = (unsigned short*)p;     p += (size_t)KS * 4 * TQ * HD * 2;
  unsigned short* pO2 = (unsigned short*)p;

  hipLaunchKernelGGL(cvtWT_kernel, dim3(512, 4), dim3(256), 0, stream,
                     Wq, Wk, Wv, WqT, WkT, WvT, lq1, lk1, lq2, lk2, lini, lam);
  hipLaunchKernelGGL(gemm_proj_kernel, dim3(MQ / 32, 3), dim3(256), 0, stream,
                     x, enc, WqT, WkT, WvT, bq, bk, bv, qb, kb, vbT);
  hipLaunchKernelGGL(attn_split_kernel, dim3(TQ / 64, 4, KS), dim3(512), 0, stream,
                     qb, kb, vbT, pO1, pO2, pstats, TK / KS);
  hipLaunchKernelGGL(attn_combine_kernel, dim3(TQ / 16, 4), dim3(256), 0, stream,
                     pO1, pO2, pstats, lam, out, KS);
  hipLaunchKernelGGL(attn_check_kernel, dim3(128), dim3(256), 0, stream,
                     qb, kb, vbT, lam, out);
}

// Round 10
// 215.520 us; speedup vs baseline: 1.0624x; 1.0624x over previous
//
#include <hip/hip_runtime.h>
#include <hip/hip_bf16.h>

// Problem: B=4, Tq=Tk=2048, E=1024, D=128, d=64. All inputs fp32, output fp32.
// Round 20: gload_lds double-buffered attn on the r18 base. r19 post-mortem:
// T14 reg-staging spilled AGAIN (VGPR 56, WRITE 115MB) — launch_bounds sets
// only min waves/EU; allocator targets 8/EU and dumps block-uniform staging
// to scratch. T14 abandoned (4 failures, same signature). Instead use the
// gemm_proj-proven pattern: global_load_lds w16 (DMA to LDS, no data regs),
// DOUBLE-buffered K/V tiles (2x16KB each = 64KB), both-sides XOR swizzle
// (r16-verified involution colbyte^=((row&7)<<4)); P reuses Kbuf[cur] after
// a post-QK barrier. Loads for tile t+1 issue before QK of tile t; the
// post-QK barrier is the drain point -> latency hidden under QK. VGPR pinned
// via amdgpu_waves_per_eu(4,4) (budget 128, live ~90).
// gemm_proj / cvtWT(+lam) / combine / tripwire unchanged from r18/r19.

#define TQ 2048
#define TK 2048
#define EMB 1024
#define HD 128
#define MQ 8192  // B*Tq rows

typedef __attribute__((ext_vector_type(8))) short short8;   // 8 bf16 = 4 VGPR
typedef __attribute__((ext_vector_type(4))) float floatx4;  // MFMA acc

__device__ __forceinline__ unsigned short f2bf(float f) {  // RNE fp32->bf16
  union { float f; unsigned u; } v; v.f = f;
  unsigned r = v.u + 0x7fffu + ((v.u >> 16) & 1u);
  return (unsigned short)(r >> 16);
}
__device__ __forceinline__ float bf2f(unsigned short s) {
  union { unsigned u; float f; } v; v.u = ((unsigned)s) << 16;
  return v.f;
}

typedef const __attribute__((address_space(1))) unsigned int guint;
typedef __attribute__((address_space(3))) unsigned int luint;
__device__ __forceinline__ void gl16(const void* g, void* l) {
  __builtin_amdgcn_global_load_lds((guint*)g, (luint*)l, 16, 0, 0);
}

// ------------------------------------- weight convert+transpose (+ lambda) ----
__global__ __launch_bounds__(256) void cvtWT_kernel(
    const float* __restrict__ Wq, const float* __restrict__ Wk,
    const float* __restrict__ Wv, unsigned short* __restrict__ WqT,
    unsigned short* __restrict__ WkT, unsigned short* __restrict__ WvT,
    const float* __restrict__ lq1, const float* __restrict__ lk1,
    const float* __restrict__ lq2, const float* __restrict__ lk2,
    const float* __restrict__ linit, float* __restrict__ lam_out) {
  const int g = blockIdx.y;
  if (g == 3) {  // lambda: one block, first wave
    if (blockIdx.x == 0 && threadIdx.x < 64) {
      int j = threadIdx.x;
      float s1 = lq1[j] * lk1[j] + lq1[j + 64] * lk1[j + 64];
      float s2 = lq2[j] * lk2[j] + lq2[j + 64] * lk2[j + 64];
      for (int off = 1; off < 64; off <<= 1) {
        s1 += __shfl_xor(s1, off);
        s2 += __shfl_xor(s2, off);
      }
      if (j == 0) lam_out[0] = __expf(s1) - __expf(s2) + linit[0];
    }
    return;
  }
  const float* W = (g == 0) ? Wq : (g == 1) ? Wk : Wv;
  unsigned short* WT = (g == 0) ? WqT : (g == 1) ? WkT : WvT;
  int idx = blockIdx.x * 256 + threadIdx.x;  // [0, 131072)
  int n = idx >> 10, k = idx & 1023;
  WT[idx] = f2bf(W[(size_t)k * HD + n]);
}

// -------------------------------------------------------- MFMA projections ----
// grid (MQ/32, 3), 256 thr (4 waves). wave w: wm=w&1 -> rows 16wm..+16,
// wn=w>>1 -> cols 64wn..+64. Per K-step (BK=64): A fp32 32x64 (8KB, 8 chunks)
// + B^T bf16 128x64 (16KB, 16 chunks) staged via global_load_lds dwordx4,
// double-buffered; 8 MFMA/wave. g=0: qb*(0.125); g=1: kb; g=2: vbT^T.
__global__ __launch_bounds__(256) void gemm_proj_kernel(
    const float* __restrict__ x, const float* __restrict__ enc,
    const unsigned short* __restrict__ WqT, const unsigned short* __restrict__ WkT,
    const unsigned short* __restrict__ WvT,
    const float* __restrict__ bq, const float* __restrict__ bk,
    const float* __restrict__ bv,
    unsigned short* __restrict__ qb, unsigned short* __restrict__ kb,
    unsigned short* __restrict__ vbT) {
  __shared__ __align__(16) float Ab[2][32 * 64];             // 16 KB, linear (no pad)
  __shared__ __align__(16) unsigned short Bb[2][128 * 64];   // 32 KB, linear (no pad)
  const int t = threadIdx.x;
  const int w = t >> 6, lane = t & 63;
  const int lo = lane & 15, quad = lane >> 4;
  const int wm = w & 1, wn = w >> 1;
  const int g = blockIdx.y;
  const size_t m0 = (size_t)blockIdx.x * 32;
  const float* A = (g == 0) ? x : enc;
  const unsigned short* BT = (g == 0) ? WqT : (g == 1) ? WkT : WvT;
  const float* bias = (g == 0) ? bq : (g == 1) ? bk : bv;

  // Per-lane staging sources, pre-swizzled so linear LDS + swizzled ds_read
  // reconstructs the original element (involution: col_byte ^= ((row&7)<<4)).
  // A: 8 chunks of 1KB (4 rows x 256B); wave w owns chunks 2w, 2w+1.
  const float* gA[2];
  int ldsAoff[2];
#pragma unroll
  for (int j = 0; j < 2; ++j) {
    int c = 2 * w + j;
    int row = 4 * c + (lane >> 4);
    int colb = ((lane & 15) * 16) ^ ((row & 7) << 4);
    gA[j] = A + (m0 + row) * EMB + (colb >> 2);
    ldsAoff[j] = c * 1024;
  }
  // B: 16 chunks of 1KB (8 rows x 128B); wave w owns chunks 4w..4w+3.
  const unsigned short* gB[4];
  int ldsBoff[4];
#pragma unroll
  for (int j = 0; j < 4; ++j) {
    int c = 4 * w + j;
    int row = 8 * c + (lane >> 3);
    int colb = ((lane & 7) * 16) ^ ((row & 7) << 4);
    gB[j] = BT + (size_t)row * EMB + (colb >> 1);
    ldsBoff[j] = c * 1024;
  }

  floatx4 acc[4];
  const floatx4 zz = {0.f, 0.f, 0.f, 0.f};
#pragma unroll
  for (int i = 0; i < 4; ++i) acc[i] = zz;

  const int xr = (lo & 7) << 4;

  auto stage = [&](int kt, int bsel) {
#pragma unroll
    for (int j = 0; j < 2; ++j) gl16(gA[j] + kt, (char*)&Ab[bsel][0] + ldsAoff[j]);
#pragma unroll
    for (int j = 0; j < 4; ++j) gl16(gB[j] + kt, (char*)&Bb[bsel][0] + ldsBoff[j]);
  };

  auto compute = [&](int bsel) {
    const char* Arow = (const char*)&Ab[bsel][(16 * wm + lo) * 64];
    const char* Bbase = (const char*)&Bb[bsel][0];
#pragma unroll
    for (int ks = 0; ks < 2; ++ks) {
      int a0 = (ks * 128 + quad * 32) ^ xr;
      float4 fa = *(const float4*)(Arow + a0);         // orig cols ks*32+q8 .. +3
      float4 fb = *(const float4*)(Arow + (a0 ^ 16));  // orig cols ks*32+q8+4 .. +7
      short8 af;
      af[0] = (short)f2bf(fa.x); af[1] = (short)f2bf(fa.y);
      af[2] = (short)f2bf(fa.z); af[3] = (short)f2bf(fa.w);
      af[4] = (short)f2bf(fb.x); af[5] = (short)f2bf(fb.y);
      af[6] = (short)f2bf(fb.z); af[7] = (short)f2bf(fb.w);
      int b0 = (ks * 64 + quad * 16) ^ xr;
#pragma unroll
      for (int nt = 0; nt < 4; ++nt) {
        int row = wn * 64 + nt * 16 + lo;
        short8 bfr = *(const short8*)(Bbase + row * 128 + b0);
        acc[nt] = __builtin_amdgcn_mfma_f32_16x16x32_bf16(af, bfr, acc[nt], 0, 0, 0);
      }
    }
  };

  // prologue: stage K-tile 0 into buf0 (syncthreads drains vmcnt+lgkmcnt)
  stage(0, 0);
  __syncthreads();

  // 2-phase pipeline, unrolled 2-deep -> static buffer indices
  for (int kt = 0; kt < EMB; kt += 128) {
    stage(kt + 64, 1);          // prefetch next tile (kt+64 <= 960, always valid)
    compute(0);                 // consume tile kt
    __syncthreads();            // drains: buf1 loads done, buf0 reads done
    if (kt + 128 < EMB) stage(kt + 128, 0);
    compute(1);                 // consume tile kt+64
    __syncthreads();
  }

  // epilogue: rows m0+16wm+quad*4+r, cols 64wn+nt*16+lo
  const int mrow = 16 * wm + quad * 4;
  if (g < 2) {
    unsigned short* Y = (g == 0) ? qb : kb;
    const float sc = (g == 0) ? 0.125f : 1.0f;
#pragma unroll
    for (int nt = 0; nt < 4; ++nt) {
      float bn = bias[wn * 64 + nt * 16 + lo];
#pragma unroll
      for (int r = 0; r < 4; ++r)
        Y[(m0 + mrow + r) * HD + wn * 64 + nt * 16 + lo] = f2bf((acc[nt][r] + bn) * sc);
    }
  } else {
#pragma unroll
    for (int nt = 0; nt < 4; ++nt) {
      float bn = bias[wn * 64 + nt * 16 + lo];
      unsigned long long pk = 0;
#pragma unroll
      for (int r = 0; r < 4; ++r)
        pk |= (unsigned long long)f2bf(acc[nt][r] + bn) << (16 * r);
      *(unsigned long long*)&vbT[(size_t)(wn * 64 + nt * 16 + lo) * MQ + m0 + mrow] = pk;
    }
  }
}

// ---------------------------------------------------- attention (key-split) ----
// Round 20: r18 group-split (512 thr, 8 waves; waves 0-3 group 1, 4-7 group 2)
// with gload_lds double-buffered K/V (64KB LDS total). Per tile: issue stage
// of t+1 into buf^1 -> QK from buf -> barrier (drain + K-read release) ->
// softmax, P into Kbuf[buf] (own wave region, swizzled) -> PV -> barrier.
// XOR involution colbyte^=((row&7)<<4) on both stage-source and ds_read.
__global__ __launch_bounds__(512)
__attribute__((amdgpu_waves_per_eu(4, 4))) void attn_split_kernel(
    const unsigned short* __restrict__ qb, const unsigned short* __restrict__ kb,
    const unsigned short* __restrict__ vbT,
    unsigned short* __restrict__ pO1, unsigned short* __restrict__ pO2,
    float2* __restrict__ pstats, int nkeys) {
  __shared__ __align__(16) unsigned short KB[2][64 * 128];   // 32 KB (P reuses)
  __shared__ __align__(16) unsigned short VB[2][128 * 64];   // 32 KB

  const int t = threadIdx.x;
  const int w = t >> 6;        // 0..7
  const int g = w >> 2;        // softmax group 0/1
  const int wv = w & 3;        // wave within group -> q-row block
  const int lane = t & 63;
  const int lo = lane & 15;
  const int quad = lane >> 4;
  const int q8 = quad * 8;
  const int xr = (lo & 7) << 4;  // read-side swizzle
  const int b = blockIdx.y;
  const int q0 = blockIdx.x * 64;
  const int ksp = blockIdx.z;
  const int kt0 = ksp * nkeys;
  const int ksTot = TK / nkeys;
  const size_t kbase = (size_t)b * TK;

  const size_t qrow = (size_t)b * TQ + q0 + wv * 16 + lo;
  short8 qf[2];
#pragma unroll
  for (int ks = 0; ks < 2; ++ks)
    qf[ks] = *(const short8*)&qb[qrow * HD + g * 64 + ks * 32 + q8];

  // Staging descriptors: each 16KB tile = 16 chunks of 1KB; wave w owns
  // chunks {w, w+8}. gl16 dest = wave-uniform base + lane*16 (linear).
  // Sources are inverse-swizzled (colb ^= (row&7)<<4) so swizzled ds_reads
  // reconstruct logical elements.
  const char* kSrc[2];
  const char* vSrc[2];
  int ldsOff[2];
#pragma unroll
  for (int j = 0; j < 2; ++j) {
    int c = w + 8 * j;
    int krow = c * 4 + (lane >> 4);                      // K row in [0,64)
    int kcolb = ((lane & 15) * 16) ^ ((krow & 7) << 4);  // byte col in [0,256)
    kSrc[j] = (const char*)&kb[(kbase + krow) * HD] + kcolb;
    int f = c * 8 + (lane >> 3);                         // V feature in [0,128)
    int vcolb = ((lane & 7) * 16) ^ ((f & 7) << 4);      // byte col in [0,128)
    vSrc[j] = (const char*)&vbT[(size_t)f * MQ + kbase] + vcolb;
    ldsOff[j] = c * 1024;
  }

  floatx4 o[8];
  const floatx4 zz = {0.f, 0.f, 0.f, 0.f};
#pragma unroll
  for (int i = 0; i < 8; ++i) o[i] = zz;
  float m[4], l[4];
#pragma unroll
  for (int r = 0; r < 4; ++r) { m[r] = -1e30f; l[r] = 0.f; }

  auto stage = [&](int kt, int bsel) {
#pragma unroll
    for (int j = 0; j < 2; ++j) {
      gl16(kSrc[j] + (size_t)kt * 256, (char*)&KB[bsel][0] + ldsOff[j]);
      gl16(vSrc[j] + (size_t)kt * 2, (char*)&VB[bsel][0] + ldsOff[j]);
    }
  };

  auto computeTile = [&](int bsel) {
    const char* Kb = (const char*)&KB[bsel][0];
    const char* Vb = (const char*)&VB[bsel][0];
    char* Pb = (char*)&KB[bsel][0] + w * 2048;

    floatx4 s[4];
#pragma unroll
    for (int i = 0; i < 4; ++i) s[i] = zz;
#pragma unroll
    for (int ks = 0; ks < 2; ++ks)
#pragma unroll
      for (int nt = 0; nt < 4; ++nt) {
        int row = nt * 16 + lo;
        int cb = (g * 128 + ks * 64 + quad * 16) ^ xr;
        short8 kf = *(const short8*)(Kb + row * 256 + cb);
        s[nt] = __builtin_amdgcn_mfma_f32_16x16x32_bf16(qf[ks], kf, s[nt], 0, 0, 0);
      }
    __syncthreads();  // all QK reads done (K buffer released for P) + drains
                      // the gl16s issued for the OTHER buffer before this tile

    float tm[4];
#pragma unroll
    for (int r = 0; r < 4; ++r) {
      float a = fmaxf(fmaxf(s[0][r], s[1][r]), fmaxf(s[2][r], s[3][r]));
#pragma unroll
      for (int oo = 1; oo < 16; oo <<= 1) a = fmaxf(a, __shfl_xor(a, oo));
      tm[r] = a;
    }
    bool grow = false;
#pragma unroll
    for (int r = 0; r < 4; ++r) grow = grow || (tm[r] > m[r] + 5.f);
    if (__any(grow)) {
#pragma unroll
      for (int r = 0; r < 4; ++r) {
        float mn = fmaxf(m[r], tm[r]);
        float al = __expf(m[r] - mn);
        m[r] = mn;
        l[r] *= al;
#pragma unroll
        for (int nt = 0; nt < 8; ++nt) o[nt][r] *= al;
      }
    }
#pragma unroll
    for (int r = 0; r < 4; ++r) {
      float ls = 0.f;
      int rr = quad * 4 + r;
      int srr = (rr & 7) << 4;
#pragma unroll
      for (int nt = 0; nt < 4; ++nt) {
        float p = __expf(s[nt][r] - m[r]);
        ls += p;
        int pb = rr * 128 + (((nt * 16 + lo) * 2) ^ srr);
        *(unsigned short*)(Pb + pb) = f2bf(p);
      }
#pragma unroll
      for (int oo = 1; oo < 16; oo <<= 1) ls += __shfl_xor(ls, oo);
      l[r] += ls;
    }

#pragma unroll
    for (int ks = 0; ks < 2; ++ks) {
      int cb = (ks * 64 + quad * 16) ^ xr;
      short8 p8 = *(const short8*)(Pb + lo * 128 + cb);
#pragma unroll
      for (int nt = 0; nt < 8; ++nt) {
        short8 vf = *(const short8*)(Vb + (nt * 16 + lo) * 128 + cb);
        o[nt] = __builtin_amdgcn_mfma_f32_16x16x32_bf16(p8, vf, o[nt], 0, 0, 0);
      }
    }
    __syncthreads();  // P/V reads done -> buffer free for restage
  };

  // prologue: tile 0 into buf0
  stage(kt0, 0);
  __syncthreads();

  // 2-deep pipeline (nkeys is a multiple of 128 for all KS in {1,2,4})
  for (int kt = kt0; kt < kt0 + nkeys; kt += 128) {
    stage(kt + 64, 1);                              // always valid
    computeTile(0);                                 // consume tile kt
    if (kt + 128 < kt0 + nkeys) stage(kt + 128, 0);
    computeTile(1);                                 // consume tile kt+64
  }

  unsigned short* Y = g ? pO2 : pO1;
#pragma unroll
  for (int r = 0; r < 4; ++r) {
    int rowb = q0 + wv * 16 + quad * 4 + r;
    size_t idx = ((size_t)(ksp * 4 + b)) * TQ + rowb;
    if (lo == 0)
      pstats[((size_t)(g * ksTot + ksp) * 4 + b) * TQ + rowb] = make_float2(m[r], l[r]);
#pragma unroll
    for (int nt = 0; nt < 8; ++nt)
      Y[idx * HD + nt * 16 + lo] = f2bf(o[nt][r]);
  }
}

// ---------------------------------------------------------------- combine ----
// pstats layout: [(g*ksn + s)*4 + b)*TQ + row] -> (m, l) per group.
__global__ __launch_bounds__(256) void attn_combine_kernel(
    const unsigned short* __restrict__ pO1, const unsigned short* __restrict__ pO2,
    const float2* __restrict__ pstats, const float* __restrict__ lam_ptr,
    float* __restrict__ out, int ksn) {
  const int t = threadIdx.x;
  const int b = blockIdx.y;
  const int row = blockIdx.x * 16 + (t >> 4);
  const int dg = t & 15;

  float m1s[8], l1s[8], m2s[8], l2s[8];
  float M1 = -1e30f, M2 = -1e30f;
  for (int s = 0; s < ksn; ++s) {
    float2 fa = pstats[((size_t)(s) * 4 + b) * TQ + row];
    float2 fb = pstats[((size_t)(ksn + s) * 4 + b) * TQ + row];
    m1s[s] = fa.x; l1s[s] = fa.y; m2s[s] = fb.x; l2s[s] = fb.y;
    M1 = fmaxf(M1, fa.x); M2 = fmaxf(M2, fb.x);
  }
  float L1 = 0.f, L2 = 0.f, e1[8], e2[8];
  for (int s = 0; s < ksn; ++s) {
    e1[s] = __expf(m1s[s] - M1); e2[s] = __expf(m2s[s] - M2);
    L1 += l1s[s] * e1[s]; L2 += l2s[s] * e2[s];
  }
  float a1[8], a2[8];
#pragma unroll
  for (int j = 0; j < 8; ++j) { a1[j] = 0.f; a2[j] = 0.f; }
  for (int s = 0; s < ksn; ++s) {
    size_t base = (((size_t)(s * 4 + b)) * TQ + row) * HD + dg * 8;
    int4 r1 = *(const int4*)&pO1[base];
    int4 r2 = *(const int4*)&pO2[base];
    const unsigned short* u1 = (const unsigned short*)&r1;
    const unsigned short* u2 = (const unsigned short*)&r2;
#pragma unroll
    for (int j = 0; j < 8; ++j) {
      a1[j] += bf2f(u1[j]) * e1[s];
      a2[j] += bf2f(u2[j]) * e2[s];
    }
  }
  const float i1 = 1.f / L1;
  const float i2 = lam_ptr[0] / L2;
  float4* op = (float4*)&out[((size_t)b * TQ + row) * HD + dg * 8];
  op[0] = make_float4(a1[0] * i1 - a2[0] * i2, a1[1] * i1 - a2[1] * i2,
                      a1[2] * i1 - a2[2] * i2, a1[3] * i1 - a2[3] * i2);
  op[1] = make_float4(a1[4] * i1 - a2[4] * i2, a1[5] * i1 - a2[5] * i2,
                      a1[6] * i1 - a2[6] * i2, a1[7] * i1 - a2[7] * i2);
}

// --------------------------------------------------------------- tripwire ----
__global__ __launch_bounds__(256) void attn_check_kernel(
    const unsigned short* __restrict__ qb, const unsigned short* __restrict__ kb,
    const unsigned short* __restrict__ vbT, const float* __restrict__ lamp,
    float* __restrict__ out) {
  __shared__ float qsh[HD];
  __shared__ float sred[4][4];
  const int t = threadIdx.x;
  const int w = t >> 6, lane = t & 63;
  const int bb = blockIdx.x & 3;
  const int q = (int)((blockIdx.x * 997u + 13u) & 2047u);
  const int dc = (int)((blockIdx.x * 37u + 5u) & 127u);

  const unsigned short* qr = &qb[((size_t)bb * TQ + q) * HD];
  if (t < HD) qsh[t] = bf2f(qr[t]);
  __syncthreads();

  float mx1 = -1e30f, mx2 = -1e30f;
  for (int it = 0; it < 8; ++it) {
    int key = t + 256 * it;
    const unsigned* kr = (const unsigned*)&kb[((size_t)bb * TK + key) * HD];
    float s1 = 0.f, s2 = 0.f;
#pragma unroll 8
    for (int du = 0; du < 32; ++du) {
      unsigned u1 = kr[du], u2 = kr[32 + du];
      s1 += qsh[2 * du] * bf2f((unsigned short)u1) +
            qsh[2 * du + 1] * bf2f((unsigned short)(u1 >> 16));
      s2 += qsh[64 + 2 * du] * bf2f((unsigned short)u2) +
            qsh[64 + 2 * du + 1] * bf2f((unsigned short)(u2 >> 16));
    }
    mx1 = fmaxf(mx1, s1); mx2 = fmaxf(mx2, s2);
  }
  for (int o = 1; o < 64; o <<= 1) {
    mx1 = fmaxf(mx1, __shfl_xor(mx1, o));
    mx2 = fmaxf(mx2, __shfl_xor(mx2, o));
  }
  if (lane == 0) { sred[0][w] = mx1; sred[1][w] = mx2; }
  __syncthreads();
  mx1 = fmaxf(fmaxf(sred[0][0], sred[0][1]), fmaxf(sred[0][2], sred[0][3]));
  mx2 = fmaxf(fmaxf(sred[1][0], sred[1][1]), fmaxf(sred[1][2], sred[1][3]));
  __syncthreads();

  float l1 = 0.f, l2 = 0.f, o1 = 0.f, o2 = 0.f;
  for (int it = 0; it < 8; ++it) {
    int key = t + 256 * it;
    const unsigned* kr = (const unsigned*)&kb[((size_t)bb * TK + key) * HD];
    float s1 = 0.f, s2 = 0.f;
#pragma unroll 8
    for (int du = 0; du < 32; ++du) {
      unsigned u1 = kr[du], u2 = kr[32 + du];
      s1 += qsh[2 * du] * bf2f((unsigned short)u1) +
            qsh[2 * du + 1] * bf2f((unsigned short)(u1 >> 16));
      s2 += qsh[64 + 2 * du] * bf2f((unsigned short)u2) +
            qsh[64 + 2 * du + 1] * bf2f((unsigned short)(u2 >> 16));
    }
    float p1 = __expf(s1 - mx1), p2 = __expf(s2 - mx2);
    float v = bf2f(vbT[(size_t)dc * MQ + bb * TK + key]);
    l1 += p1; l2 += p2; o1 += p1 * v; o2 += p2 * v;
  }
  for (int o = 1; o < 64; o <<= 1) {
    l1 += __shfl_xor(l1, o); l2 += __shfl_xor(l2, o);
    o1 += __shfl_xor(o1, o); o2 += __shfl_xor(o2, o);
  }
  if (lane == 0) { sred[0][w] = l1; sred[1][w] = l2; sred[2][w] = o1; sred[3][w] = o2; }
  __syncthreads();
  if (t == 0) {
    l1 = sred[0][0] + sred[0][1] + sred[0][2] + sred[0][3];
    l2 = sred[1][0] + sred[1][1] + sred[1][2] + sred[1][3];
    o1 = sred[2][0] + sred[2][1] + sred[2][2] + sred[2][3];
    o2 = sred[3][0] + sred[3][1] + sred[3][2] + sred[3][3];
    float res = o1 / l1 - lamp[0] * (o2 / l2);
    float got = out[((size_t)bb * TQ + q) * HD + dc];
    if (!(fabsf(res - got) <= 0.02f)) out[0] = 1.0e7f;
  }
}

extern "C" void kernel_launch(void* const* d_in, const int* in_sizes, int n_in,
                              void* d_out, int out_size, void* d_ws, size_t ws_size,
                              hipStream_t stream) {
  const float* x    = (const float*)d_in[0];
  const float* enc  = (const float*)d_in[1];
  const float* Wq   = (const float*)d_in[2];
  const float* bq   = (const float*)d_in[3];
  const float* Wk   = (const float*)d_in[4];
  const float* bk   = (const float*)d_in[5];
  const float* Wv   = (const float*)d_in[6];
  const float* bv   = (const float*)d_in[7];
  const float* lq1  = (const float*)d_in[8];
  const float* lk1  = (const float*)d_in[9];
  const float* lq2  = (const float*)d_in[10];
  const float* lk2  = (const float*)d_in[11];
  const float* lini = (const float*)d_in[12];
  float* out = (float*)d_out;

  char* p = (char*)d_ws;
  float* lam = (float*)p;                       p += 256;
  unsigned short* qb  = (unsigned short*)p;     p += (size_t)MQ * HD * 2;
  unsigned short* kb  = (unsigned short*)p;     p += (size_t)MQ * HD * 2;
  unsigned short* vbT = (unsigned short*)p;     p += (size_t)MQ * HD * 2;  // [128][8192]
  unsigned short* WqT = (unsigned short*)p;     p += (size_t)EMB * HD * 2;
  unsigned short* WkT = (unsigned short*)p;     p += (size_t)EMB * HD * 2;
  unsigned short* WvT = (unsigned short*)p;     p += (size_t)EMB * HD * 2;
  const size_t base_need = (size_t)(p - (char*)d_ws);

  // per-KS: stats 2 groups x 4 x TQ x sizeof(float2) (= 4*TQ*16) + pO1/pO2
  const size_t per_ks = (size_t)4 * TQ * 16 + 2ull * 4 * TQ * HD * 2;
  int KS = 4;
  while (KS > 1 && base_need + (size_t)KS * per_ks > ws_size) KS >>= 1;

  float2* pstats = (float2*)p;                  p += (size_t)KS * 4 * TQ * 16;
  unsigned short* pO1 = (unsigned short*)p;     p += (size_t)KS * 4 * TQ * HD * 2;
  unsigned short* pO2 = (unsigned short*)p;

  hipLaunchKernelGGL(cvtWT_kernel, dim3(512, 4), dim3(256), 0, stream,
                     Wq, Wk, Wv, WqT, WkT, WvT, lq1, lk1, lq2, lk2, lini, lam);
  hipLaunchKernelGGL(gemm_proj_kernel, dim3(MQ / 32, 3), dim3(256), 0, stream,
                     x, enc, WqT, WkT, WvT, bq, bk, bv, qb, kb, vbT);
  hipLaunchKernelGGL(attn_split_kernel, dim3(TQ / 64, 4, KS), dim3(512), 0, stream,
                     qb, kb, vbT, pO1, pO2, pstats, TK / KS);
  hipLaunchKernelGGL(attn_combine_kernel, dim3(TQ / 16, 4), dim3(256), 0, stream,
                     pO1, pO2, pstats, lam, out, KS);
  hipLaunchKernelGGL(attn_check_kernel, dim3(128), dim3(256), 0, stream,
                     qb, kb, vbT, lam, out);
}

// Round 11
// 178.384 us; speedup vs baseline: 1.2836x; 1.2082x over previous
//
#include <hip/hip_runtime.h>
#include <hip/hip_bf16.h>

// Problem: B=4, Tq=Tk=2048, E=1024, D=128, d=64. All inputs fp32, output fp32.
// Round 21: bank r18 (209.0us best; attn 44.1us, VGPR 52, no spill) and
// remove the attn_check tripwire. r20 post-mortem: gload_lds dbuf ALSO
// spilled (WRITE +14.3MB = 512x512x~56B scratch for staging descriptors,
// FETCH +7.2MB) — six staging restructures, six spills/regressions; at 34%
// occupancy inter-block TLP already overlaps the barrier drain (m114), so
// intra-block pipelining has no headroom at this structure. attn_check is
// redundant with the harness's own JAX-reference verification and costs a
// serialized latency-exposed dispatch (128 blocks x 2 full key passes).
// attn_split / gemm_proj / cvtWT(+lam) / combine are byte-identical to r18.

#define TQ 2048
#define TK 2048
#define EMB 1024
#define HD 128
#define MQ 8192  // B*Tq rows

typedef __attribute__((ext_vector_type(8))) short short8;   // 8 bf16 = 4 VGPR
typedef __attribute__((ext_vector_type(4))) float floatx4;  // MFMA acc

__device__ __forceinline__ unsigned short f2bf(float f) {  // RNE fp32->bf16
  union { float f; unsigned u; } v; v.f = f;
  unsigned r = v.u + 0x7fffu + ((v.u >> 16) & 1u);
  return (unsigned short)(r >> 16);
}
__device__ __forceinline__ float bf2f(unsigned short s) {
  union { unsigned u; float f; } v; v.u = ((unsigned)s) << 16;
  return v.f;
}

typedef const __attribute__((address_space(1))) unsigned int guint;
typedef __attribute__((address_space(3))) unsigned int luint;
__device__ __forceinline__ void gl16(const void* g, void* l) {
  __builtin_amdgcn_global_load_lds((guint*)g, (luint*)l, 16, 0, 0);
}

// ------------------------------------- weight convert+transpose (+ lambda) ----
__global__ __launch_bounds__(256) void cvtWT_kernel(
    const float* __restrict__ Wq, const float* __restrict__ Wk,
    const float* __restrict__ Wv, unsigned short* __restrict__ WqT,
    unsigned short* __restrict__ WkT, unsigned short* __restrict__ WvT,
    const float* __restrict__ lq1, const float* __restrict__ lk1,
    const float* __restrict__ lq2, const float* __restrict__ lk2,
    const float* __restrict__ linit, float* __restrict__ lam_out) {
  const int g = blockIdx.y;
  if (g == 3) {  // lambda: one block, first wave
    if (blockIdx.x == 0 && threadIdx.x < 64) {
      int j = threadIdx.x;
      float s1 = lq1[j] * lk1[j] + lq1[j + 64] * lk1[j + 64];
      float s2 = lq2[j] * lk2[j] + lq2[j + 64] * lk2[j + 64];
      for (int off = 1; off < 64; off <<= 1) {
        s1 += __shfl_xor(s1, off);
        s2 += __shfl_xor(s2, off);
      }
      if (j == 0) lam_out[0] = __expf(s1) - __expf(s2) + linit[0];
    }
    return;
  }
  const float* W = (g == 0) ? Wq : (g == 1) ? Wk : Wv;
  unsigned short* WT = (g == 0) ? WqT : (g == 1) ? WkT : WvT;
  int idx = blockIdx.x * 256 + threadIdx.x;  // [0, 131072)
  int n = idx >> 10, k = idx & 1023;
  WT[idx] = f2bf(W[(size_t)k * HD + n]);
}

// -------------------------------------------------------- MFMA projections ----
// grid (MQ/32, 3), 256 thr (4 waves). wave w: wm=w&1 -> rows 16wm..+16,
// wn=w>>1 -> cols 64wn..+64. Per K-step (BK=64): A fp32 32x64 (8KB, 8 chunks)
// + B^T bf16 128x64 (16KB, 16 chunks) staged via global_load_lds dwordx4,
// double-buffered; 8 MFMA/wave. g=0: qb*(0.125); g=1: kb; g=2: vbT^T.
__global__ __launch_bounds__(256) void gemm_proj_kernel(
    const float* __restrict__ x, const float* __restrict__ enc,
    const unsigned short* __restrict__ WqT, const unsigned short* __restrict__ WkT,
    const unsigned short* __restrict__ WvT,
    const float* __restrict__ bq, const float* __restrict__ bk,
    const float* __restrict__ bv,
    unsigned short* __restrict__ qb, unsigned short* __restrict__ kb,
    unsigned short* __restrict__ vbT) {
  __shared__ __align__(16) float Ab[2][32 * 64];             // 16 KB, linear (no pad)
  __shared__ __align__(16) unsigned short Bb[2][128 * 64];   // 32 KB, linear (no pad)
  const int t = threadIdx.x;
  const int w = t >> 6, lane = t & 63;
  const int lo = lane & 15, quad = lane >> 4;
  const int wm = w & 1, wn = w >> 1;
  const int g = blockIdx.y;
  const size_t m0 = (size_t)blockIdx.x * 32;
  const float* A = (g == 0) ? x : enc;
  const unsigned short* BT = (g == 0) ? WqT : (g == 1) ? WkT : WvT;
  const float* bias = (g == 0) ? bq : (g == 1) ? bk : bv;

  // Per-lane staging sources, pre-swizzled so linear LDS + swizzled ds_read
  // reconstructs the original element (involution: col_byte ^= ((row&7)<<4)).
  // A: 8 chunks of 1KB (4 rows x 256B); wave w owns chunks 2w, 2w+1.
  const float* gA[2];
  int ldsAoff[2];
#pragma unroll
  for (int j = 0; j < 2; ++j) {
    int c = 2 * w + j;
    int row = 4 * c + (lane >> 4);
    int colb = ((lane & 15) * 16) ^ ((row & 7) << 4);
    gA[j] = A + (m0 + row) * EMB + (colb >> 2);
    ldsAoff[j] = c * 1024;
  }
  // B: 16 chunks of 1KB (8 rows x 128B); wave w owns chunks 4w..4w+3.
  const unsigned short* gB[4];
  int ldsBoff[4];
#pragma unroll
  for (int j = 0; j < 4; ++j) {
    int c = 4 * w + j;
    int row = 8 * c + (lane >> 3);
    int colb = ((lane & 7) * 16) ^ ((row & 7) << 4);
    gB[j] = BT + (size_t)row * EMB + (colb >> 1);
    ldsBoff[j] = c * 1024;
  }

  floatx4 acc[4];
  const floatx4 zz = {0.f, 0.f, 0.f, 0.f};
#pragma unroll
  for (int i = 0; i < 4; ++i) acc[i] = zz;

  const int xr = (lo & 7) << 4;

  auto stage = [&](int kt, int bsel) {
#pragma unroll
    for (int j = 0; j < 2; ++j) gl16(gA[j] + kt, (char*)&Ab[bsel][0] + ldsAoff[j]);
#pragma unroll
    for (int j = 0; j < 4; ++j) gl16(gB[j] + kt, (char*)&Bb[bsel][0] + ldsBoff[j]);
  };

  auto compute = [&](int bsel) {
    const char* Arow = (const char*)&Ab[bsel][(16 * wm + lo) * 64];
    const char* Bbase = (const char*)&Bb[bsel][0];
#pragma unroll
    for (int ks = 0; ks < 2; ++ks) {
      int a0 = (ks * 128 + quad * 32) ^ xr;
      float4 fa = *(const float4*)(Arow + a0);         // orig cols ks*32+q8 .. +3
      float4 fb = *(const float4*)(Arow + (a0 ^ 16));  // orig cols ks*32+q8+4 .. +7
      short8 af;
      af[0] = (short)f2bf(fa.x); af[1] = (short)f2bf(fa.y);
      af[2] = (short)f2bf(fa.z); af[3] = (short)f2bf(fa.w);
      af[4] = (short)f2bf(fb.x); af[5] = (short)f2bf(fb.y);
      af[6] = (short)f2bf(fb.z); af[7] = (short)f2bf(fb.w);
      int b0 = (ks * 64 + quad * 16) ^ xr;
#pragma unroll
      for (int nt = 0; nt < 4; ++nt) {
        int row = wn * 64 + nt * 16 + lo;
        short8 bfr = *(const short8*)(Bbase + row * 128 + b0);
        acc[nt] = __builtin_amdgcn_mfma_f32_16x16x32_bf16(af, bfr, acc[nt], 0, 0, 0);
      }
    }
  };

  // prologue: stage K-tile 0 into buf0 (syncthreads drains vmcnt+lgkmcnt)
  stage(0, 0);
  __syncthreads();

  // 2-phase pipeline, unrolled 2-deep -> static buffer indices
  for (int kt = 0; kt < EMB; kt += 128) {
    stage(kt + 64, 1);          // prefetch next tile (kt+64 <= 960, always valid)
    compute(0);                 // consume tile kt
    __syncthreads();            // drains: buf1 loads done, buf0 reads done
    if (kt + 128 < EMB) stage(kt + 128, 0);
    compute(1);                 // consume tile kt+64
    __syncthreads();
  }

  // epilogue: rows m0+16wm+quad*4+r, cols 64wn+nt*16+lo
  const int mrow = 16 * wm + quad * 4;
  if (g < 2) {
    unsigned short* Y = (g == 0) ? qb : kb;
    const float sc = (g == 0) ? 0.125f : 1.0f;
#pragma unroll
    for (int nt = 0; nt < 4; ++nt) {
      float bn = bias[wn * 64 + nt * 16 + lo];
#pragma unroll
      for (int r = 0; r < 4; ++r)
        Y[(m0 + mrow + r) * HD + wn * 64 + nt * 16 + lo] = f2bf((acc[nt][r] + bn) * sc);
    }
  } else {
#pragma unroll
    for (int nt = 0; nt < 4; ++nt) {
      float bn = bias[wn * 64 + nt * 16 + lo];
      unsigned long long pk = 0;
#pragma unroll
      for (int r = 0; r < 4; ++r)
        pk |= (unsigned long long)f2bf(acc[nt][r] + bn) << (16 * r);
      *(unsigned long long*)&vbT[(size_t)(wn * 64 + nt * 16 + lo) * MQ + m0 + mrow] = pk;
    }
  }
}

// ---------------------------------------------------- attention (key-split) ----
// r18 kernel verbatim (best measured: 44.1us, VGPR 52, no spill).
// 512 thr / 8 waves. Waves 0-3: group 1 (q/K cols 0..63), waves 4-7: group 2
// (cols 64..127); wave wv in a group owns q-rows q0+16wv..+16. Shared K/V
// tile staged by all 512 threads. Per-wave 24 MFMA/tile. T13 defer-max.
__global__ __launch_bounds__(512, 4) void attn_split_kernel(
    const unsigned short* __restrict__ qb, const unsigned short* __restrict__ kb,
    const unsigned short* __restrict__ vbT,
    unsigned short* __restrict__ pO1, unsigned short* __restrict__ pO2,
    float2* __restrict__ pstats, int nkeys) {
  __shared__ __align__(16) unsigned short Kls[64][136];   // 17.4 KB
  __shared__ __align__(16) unsigned short Vt[128][72];    // 18.4 KB
  __shared__ __align__(16) unsigned short Pls[8][16][72]; // 18.4 KB

  const int t = threadIdx.x;
  const int w = t >> 6;        // 0..7
  const int g = w >> 2;        // softmax group 0/1
  const int wv = w & 3;        // wave within group -> q-row block
  const int lane = t & 63;
  const int lo = lane & 15;
  const int quad = lane >> 4;
  const int q8 = quad * 8;
  const int b = blockIdx.y;
  const int q0 = blockIdx.x * 64;
  const int ksp = blockIdx.z;
  const int kt0 = ksp * nkeys;
  const int ksTot = TK / nkeys;
  const size_t kbase = (size_t)b * TK;

  const size_t qrow = (size_t)b * TQ + q0 + wv * 16 + lo;
  short8 qf[2];
#pragma unroll
  for (int ks = 0; ks < 2; ++ks)
    qf[ks] = *(const short8*)&qb[qrow * HD + g * 64 + ks * 32 + q8];

  floatx4 o[8];
  const floatx4 zz = {0.f, 0.f, 0.f, 0.f};
#pragma unroll
  for (int i = 0; i < 8; ++i) o[i] = zz;
  float m[4], l[4];
#pragma unroll
  for (int r = 0; r < 4; ++r) { m[r] = -1e30f; l[r] = 0.f; }

  for (int kt = kt0; kt < kt0 + nkeys; kt += 64) {
    // cooperative staging: 1024 K-chunks + 1024 V-chunks, 512 threads x 2 iters
#pragma unroll
    for (int i = 0; i < 2; ++i) {
      int c = t + 512 * i;
      int key = c >> 4, f0 = (c & 15) * 8;
      *(int4*)&Kls[key][f0] =
          *(const int4*)&kb[(kbase + kt + key) * HD + f0];
      int f = c >> 3, k0 = (c & 7) * 8;
      *(int4*)&Vt[f][k0] =
          *(const int4*)&vbT[(size_t)f * MQ + kbase + kt + k0];
    }
    __syncthreads();

    floatx4 s[4];
#pragma unroll
    for (int i = 0; i < 4; ++i) s[i] = zz;
#pragma unroll
    for (int ks = 0; ks < 2; ++ks)
#pragma unroll
      for (int nt = 0; nt < 4; ++nt) {
        short8 kf = *(const short8*)&Kls[nt * 16 + lo][g * 64 + ks * 32 + q8];
        s[nt] = __builtin_amdgcn_mfma_f32_16x16x32_bf16(qf[ks], kf, s[nt], 0, 0, 0);
      }

    // per-row tile maxes (uniform within 16-lane groups after reduce)
    float tm[4];
#pragma unroll
    for (int r = 0; r < 4; ++r) {
      float a = fmaxf(fmaxf(s[0][r], s[1][r]), fmaxf(s[2][r], s[3][r]));
#pragma unroll
      for (int oo = 1; oo < 16; oo <<= 1) a = fmaxf(a, __shfl_xor(a, oo));
      tm[r] = a;
    }
    // T13 defer-max: rescale only when some row grew by >5 (wave-uniform)
    bool grow = false;
#pragma unroll
    for (int r = 0; r < 4; ++r) grow = grow || (tm[r] > m[r] + 5.f);
    if (__any(grow)) {
#pragma unroll
      for (int r = 0; r < 4; ++r) {
        float mn = fmaxf(m[r], tm[r]);
        float al = __expf(m[r] - mn);
        m[r] = mn;
        l[r] *= al;
#pragma unroll
        for (int nt = 0; nt < 8; ++nt) o[nt][r] *= al;
      }
    }
#pragma unroll
    for (int r = 0; r < 4; ++r) {
      float ls = 0.f;
#pragma unroll
      for (int nt = 0; nt < 4; ++nt) {
        float p = __expf(s[nt][r] - m[r]);
        ls += p;
        Pls[w][quad * 4 + r][nt * 16 + lo] = f2bf(p);
      }
#pragma unroll
      for (int oo = 1; oo < 16; oo <<= 1) ls += __shfl_xor(ls, oo);
      l[r] += ls;
    }

#pragma unroll
    for (int ks = 0; ks < 2; ++ks) {
      short8 p8 = *(const short8*)&Pls[w][lo][ks * 32 + q8];
#pragma unroll
      for (int nt = 0; nt < 8; ++nt) {
        short8 vf = *(const short8*)&Vt[nt * 16 + lo][ks * 32 + q8];
        o[nt] = __builtin_amdgcn_mfma_f32_16x16x32_bf16(p8, vf, o[nt], 0, 0, 0);
      }
    }
    __syncthreads();
  }

  unsigned short* Y = g ? pO2 : pO1;
#pragma unroll
  for (int r = 0; r < 4; ++r) {
    int rowb = q0 + wv * 16 + quad * 4 + r;
    size_t idx = ((size_t)(ksp * 4 + b)) * TQ + rowb;
    if (lo == 0)
      pstats[((size_t)(g * ksTot + ksp) * 4 + b) * TQ + rowb] = make_float2(m[r], l[r]);
#pragma unroll
    for (int nt = 0; nt < 8; ++nt)
      Y[idx * HD + nt * 16 + lo] = f2bf(o[nt][r]);
  }
}

// ---------------------------------------------------------------- combine ----
// pstats layout: [(g*ksn + s)*4 + b)*TQ + row] -> (m, l) per group.
__global__ __launch_bounds__(256) void attn_combine_kernel(
    const unsigned short* __restrict__ pO1, const unsigned short* __restrict__ pO2,
    const float2* __restrict__ pstats, const float* __restrict__ lam_ptr,
    float* __restrict__ out, int ksn) {
  const int t = threadIdx.x;
  const int b = blockIdx.y;
  const int row = blockIdx.x * 16 + (t >> 4);
  const int dg = t & 15;

  float m1s[8], l1s[8], m2s[8], l2s[8];
  float M1 = -1e30f, M2 = -1e30f;
  for (int s = 0; s < ksn; ++s) {
    float2 fa = pstats[((size_t)(s) * 4 + b) * TQ + row];
    float2 fb = pstats[((size_t)(ksn + s) * 4 + b) * TQ + row];
    m1s[s] = fa.x; l1s[s] = fa.y; m2s[s] = fb.x; l2s[s] = fb.y;
    M1 = fmaxf(M1, fa.x); M2 = fmaxf(M2, fb.x);
  }
  float L1 = 0.f, L2 = 0.f, e1[8], e2[8];
  for (int s = 0; s < ksn; ++s) {
    e1[s] = __expf(m1s[s] - M1); e2[s] = __expf(m2s[s] - M2);
    L1 += l1s[s] * e1[s]; L2 += l2s[s] * e2[s];
  }
  float a1[8], a2[8];
#pragma unroll
  for (int j = 0; j < 8; ++j) { a1[j] = 0.f; a2[j] = 0.f; }
  for (int s = 0; s < ksn; ++s) {
    size_t base = (((size_t)(s * 4 + b)) * TQ + row) * HD + dg * 8;
    int4 r1 = *(const int4*)&pO1[base];
    int4 r2 = *(const int4*)&pO2[base];
    const unsigned short* u1 = (const unsigned short*)&r1;
    const unsigned short* u2 = (const unsigned short*)&r2;
#pragma unroll
    for (int j = 0; j < 8; ++j) {
      a1[j] += bf2f(u1[j]) * e1[s];
      a2[j] += bf2f(u2[j]) * e2[s];
    }
  }
  const float i1 = 1.f / L1;
  const float i2 = lam_ptr[0] / L2;
  float4* op = (float4*)&out[((size_t)b * TQ + row) * HD + dg * 8];
  op[0] = make_float4(a1[0] * i1 - a2[0] * i2, a1[1] * i1 - a2[1] * i2,
                      a1[2] * i1 - a2[2] * i2, a1[3] * i1 - a2[3] * i2);
  op[1] = make_float4(a1[4] * i1 - a2[4] * i2, a1[5] * i1 - a2[5] * i2,
                      a1[6] * i1 - a2[6] * i2, a1[7] * i1 - a2[7] * i2);
}

extern "C" void kernel_launch(void* const* d_in, const int* in_sizes, int n_in,
                              void* d_out, int out_size, void* d_ws, size_t ws_size,
                              hipStream_t stream) {
  const float* x    = (const float*)d_in[0];
  const float* enc  = (const float*)d_in[1];
  const float* Wq   = (const float*)d_in[2];
  const float* bq   = (const float*)d_in[3];
  const float* Wk   = (const float*)d_in[4];
  const float* bk   = (const float*)d_in[5];
  const float* Wv   = (const float*)d_in[6];
  const float* bv   = (const float*)d_in[7];
  const float* lq1  = (const float*)d_in[8];
  const float* lk1  = (const float*)d_in[9];
  const float* lq2  = (const float*)d_in[10];
  const float* lk2  = (const float*)d_in[11];
  const float* lini = (const float*)d_in[12];
  float* out = (float*)d_out;

  char* p = (char*)d_ws;
  float* lam = (float*)p;                       p += 256;
  unsigned short* qb  = (unsigned short*)p;     p += (size_t)MQ * HD * 2;
  unsigned short* kb  = (unsigned short*)p;     p += (size_t)MQ * HD * 2;
  unsigned short* vbT = (unsigned short*)p;     p += (size_t)MQ * HD * 2;  // [128][8192]
  unsigned short* WqT = (unsigned short*)p;     p += (size_t)EMB * HD * 2;
  unsigned short* WkT = (unsigned short*)p;     p += (size_t)EMB * HD * 2;
  unsigned short* WvT = (unsigned short*)p;     p += (size_t)EMB * HD * 2;
  const size_t base_need = (size_t)(p - (char*)d_ws);

  // per-KS: stats 2 groups x 4 x TQ x sizeof(float2) (= 4*TQ*16) + pO1/pO2
  const size_t per_ks = (size_t)4 * TQ * 16 + 2ull * 4 * TQ * HD * 2;
  int KS = 4;
  while (KS > 1 && base_need + (size_t)KS * per_ks > ws_size) KS >>= 1;

  float2* pstats = (float2*)p;                  p += (size_t)KS * 4 * TQ * 16;
  unsigned short* pO1 = (unsigned short*)p;     p += (size_t)KS * 4 * TQ * HD * 2;
  unsigned short* pO2 = (unsigned short*)p;

  hipLaunchKernelGGL(cvtWT_kernel, dim3(512, 4), dim3(256), 0, stream,
                     Wq, Wk, Wv, WqT, WkT, WvT, lq1, lk1, lq2, lk2, lini, lam);
  hipLaunchKernelGGL(gemm_proj_kernel, dim3(MQ / 32, 3), dim3(256), 0, stream,
                     x, enc, WqT, WkT, WvT, bq, bk, bv, qb, kb, vbT);
  hipLaunchKernelGGL(attn_split_kernel, dim3(TQ / 64, 4, KS), dim3(512), 0, stream,
                     qb, kb, vbT, pO1, pO2, pstats, TK / KS);
  hipLaunchKernelGGL(attn_combine_kernel, dim3(TQ / 16, 4), dim3(256), 0, stream,
                     pO1, pO2, pstats, lam, out, KS);
}

// Round 12
// 177.759 us; speedup vs baseline: 1.2881x; 1.0035x over previous
//
#include <hip/hip_runtime.h>
#include <hip/hip_bf16.h>

// Problem: B=4, Tq=Tk=2048, E=1024, D=128, d=64. All inputs fp32, output fp32.
// Round 22: attn occupancy + softmax diet on the r21 base (178.4us banked).
// r21 post-mortem: tripwire was ~30us. attn_split back to 43.4us, Occ 31%,
// MFMA floor ~9us -> still latency-bound. Changes (attn_split only):
//  (a) LDS diet via XOR swizzle colbyte^=((row&7)<<4) (both sides, manual
//      per-lane writes) replacing +8-short padding: 54,272 -> 49,152 B.
//      Padded rows (68dw) collide lo0/lo8 anyway; swizzle is 2-way-free.
//  (b) KS=8 -> 1024 blocks -> 3 blocks/CU now actually fit (r15's KS=8
//      failed only because 54.3KB blocked the 3rd block).
//  (c) cheap grow-check: __any(lane-max > m+5) == reduced check; 16-lane
//      max reduce moves to the rare rescale path.
//  (d) deferred l-reduce: per-lane partials, one 16-lane reduce in epilogue.
//      (c)+(d) remove ~32 shfl ops/tile from the common path. Numerics:
//      same sums, different association (fp32 noise ~1e-6).
// gemm_proj / cvtWT(+lam) / combine byte-identical to r21 (combine arrays
// already sized for KS=8).

#define TQ 2048
#define TK 2048
#define EMB 1024
#define HD 128
#define MQ 8192  // B*Tq rows

typedef __attribute__((ext_vector_type(8))) short short8;   // 8 bf16 = 4 VGPR
typedef __attribute__((ext_vector_type(4))) float floatx4;  // MFMA acc

__device__ __forceinline__ unsigned short f2bf(float f) {  // RNE fp32->bf16
  union { float f; unsigned u; } v; v.f = f;
  unsigned r = v.u + 0x7fffu + ((v.u >> 16) & 1u);
  return (unsigned short)(r >> 16);
}
__device__ __forceinline__ float bf2f(unsigned short s) {
  union { unsigned u; float f; } v; v.u = ((unsigned)s) << 16;
  return v.f;
}

typedef const __attribute__((address_space(1))) unsigned int guint;
typedef __attribute__((address_space(3))) unsigned int luint;
__device__ __forceinline__ void gl16(const void* g, void* l) {
  __builtin_amdgcn_global_load_lds((guint*)g, (luint*)l, 16, 0, 0);
}

// ------------------------------------- weight convert+transpose (+ lambda) ----
__global__ __launch_bounds__(256) void cvtWT_kernel(
    const float* __restrict__ Wq, const float* __restrict__ Wk,
    const float* __restrict__ Wv, unsigned short* __restrict__ WqT,
    unsigned short* __restrict__ WkT, unsigned short* __restrict__ WvT,
    const float* __restrict__ lq1, const float* __restrict__ lk1,
    const float* __restrict__ lq2, const float* __restrict__ lk2,
    const float* __restrict__ linit, float* __restrict__ lam_out) {
  const int g = blockIdx.y;
  if (g == 3) {  // lambda: one block, first wave
    if (blockIdx.x == 0 && threadIdx.x < 64) {
      int j = threadIdx.x;
      float s1 = lq1[j] * lk1[j] + lq1[j + 64] * lk1[j + 64];
      float s2 = lq2[j] * lk2[j] + lq2[j + 64] * lk2[j + 64];
      for (int off = 1; off < 64; off <<= 1) {
        s1 += __shfl_xor(s1, off);
        s2 += __shfl_xor(s2, off);
      }
      if (j == 0) lam_out[0] = __expf(s1) - __expf(s2) + linit[0];
    }
    return;
  }
  const float* W = (g == 0) ? Wq : (g == 1) ? Wk : Wv;
  unsigned short* WT = (g == 0) ? WqT : (g == 1) ? WkT : WvT;
  int idx = blockIdx.x * 256 + threadIdx.x;  // [0, 131072)
  int n = idx >> 10, k = idx & 1023;
  WT[idx] = f2bf(W[(size_t)k * HD + n]);
}

// -------------------------------------------------------- MFMA projections ----
// grid (MQ/32, 3), 256 thr (4 waves). wave w: wm=w&1 -> rows 16wm..+16,
// wn=w>>1 -> cols 64wn..+64. Per K-step (BK=64): A fp32 32x64 (8KB, 8 chunks)
// + B^T bf16 128x64 (16KB, 16 chunks) staged via global_load_lds dwordx4,
// double-buffered; 8 MFMA/wave. g=0: qb*(0.125); g=1: kb; g=2: vbT^T.
__global__ __launch_bounds__(256) void gemm_proj_kernel(
    const float* __restrict__ x, const float* __restrict__ enc,
    const unsigned short* __restrict__ WqT, const unsigned short* __restrict__ WkT,
    const unsigned short* __restrict__ WvT,
    const float* __restrict__ bq, const float* __restrict__ bk,
    const float* __restrict__ bv,
    unsigned short* __restrict__ qb, unsigned short* __restrict__ kb,
    unsigned short* __restrict__ vbT) {
  __shared__ __align__(16) float Ab[2][32 * 64];             // 16 KB, linear (no pad)
  __shared__ __align__(16) unsigned short Bb[2][128 * 64];   // 32 KB, linear (no pad)
  const int t = threadIdx.x;
  const int w = t >> 6, lane = t & 63;
  const int lo = lane & 15, quad = lane >> 4;
  const int wm = w & 1, wn = w >> 1;
  const int g = blockIdx.y;
  const size_t m0 = (size_t)blockIdx.x * 32;
  const float* A = (g == 0) ? x : enc;
  const unsigned short* BT = (g == 0) ? WqT : (g == 1) ? WkT : WvT;
  const float* bias = (g == 0) ? bq : (g == 1) ? bk : bv;

  // Per-lane staging sources, pre-swizzled so linear LDS + swizzled ds_read
  // reconstructs the original element (involution: col_byte ^= ((row&7)<<4)).
  // A: 8 chunks of 1KB (4 rows x 256B); wave w owns chunks 2w, 2w+1.
  const float* gA[2];
  int ldsAoff[2];
#pragma unroll
  for (int j = 0; j < 2; ++j) {
    int c = 2 * w + j;
    int row = 4 * c + (lane >> 4);
    int colb = ((lane & 15) * 16) ^ ((row & 7) << 4);
    gA[j] = A + (m0 + row) * EMB + (colb >> 2);
    ldsAoff[j] = c * 1024;
  }
  // B: 16 chunks of 1KB (8 rows x 128B); wave w owns chunks 4w..4w+3.
  const unsigned short* gB[4];
  int ldsBoff[4];
#pragma unroll
  for (int j = 0; j < 4; ++j) {
    int c = 4 * w + j;
    int row = 8 * c + (lane >> 3);
    int colb = ((lane & 7) * 16) ^ ((row & 7) << 4);
    gB[j] = BT + (size_t)row * EMB + (colb >> 1);
    ldsBoff[j] = c * 1024;
  }

  floatx4 acc[4];
  const floatx4 zz = {0.f, 0.f, 0.f, 0.f};
#pragma unroll
  for (int i = 0; i < 4; ++i) acc[i] = zz;

  const int xr = (lo & 7) << 4;

  auto stage = [&](int kt, int bsel) {
#pragma unroll
    for (int j = 0; j < 2; ++j) gl16(gA[j] + kt, (char*)&Ab[bsel][0] + ldsAoff[j]);
#pragma unroll
    for (int j = 0; j < 4; ++j) gl16(gB[j] + kt, (char*)&Bb[bsel][0] + ldsBoff[j]);
  };

  auto compute = [&](int bsel) {
    const char* Arow = (const char*)&Ab[bsel][(16 * wm + lo) * 64];
    const char* Bbase = (const char*)&Bb[bsel][0];
#pragma unroll
    for (int ks = 0; ks < 2; ++ks) {
      int a0 = (ks * 128 + quad * 32) ^ xr;
      float4 fa = *(const float4*)(Arow + a0);         // orig cols ks*32+q8 .. +3
      float4 fb = *(const float4*)(Arow + (a0 ^ 16));  // orig cols ks*32+q8+4 .. +7
      short8 af;
      af[0] = (short)f2bf(fa.x); af[1] = (short)f2bf(fa.y);
      af[2] = (short)f2bf(fa.z); af[3] = (short)f2bf(fa.w);
      af[4] = (short)f2bf(fb.x); af[5] = (short)f2bf(fb.y);
      af[6] = (short)f2bf(fb.z); af[7] = (short)f2bf(fb.w);
      int b0 = (ks * 64 + quad * 16) ^ xr;
#pragma unroll
      for (int nt = 0; nt < 4; ++nt) {
        int row = wn * 64 + nt * 16 + lo;
        short8 bfr = *(const short8*)(Bbase + row * 128 + b0);
        acc[nt] = __builtin_amdgcn_mfma_f32_16x16x32_bf16(af, bfr, acc[nt], 0, 0, 0);
      }
    }
  };

  // prologue: stage K-tile 0 into buf0 (syncthreads drains vmcnt+lgkmcnt)
  stage(0, 0);
  __syncthreads();

  // 2-phase pipeline, unrolled 2-deep -> static buffer indices
  for (int kt = 0; kt < EMB; kt += 128) {
    stage(kt + 64, 1);          // prefetch next tile (kt+64 <= 960, always valid)
    compute(0);                 // consume tile kt
    __syncthreads();            // drains: buf1 loads done, buf0 reads done
    if (kt + 128 < EMB) stage(kt + 128, 0);
    compute(1);                 // consume tile kt+64
    __syncthreads();
  }

  // epilogue: rows m0+16wm+quad*4+r, cols 64wn+nt*16+lo
  const int mrow = 16 * wm + quad * 4;
  if (g < 2) {
    unsigned short* Y = (g == 0) ? qb : kb;
    const float sc = (g == 0) ? 0.125f : 1.0f;
#pragma unroll
    for (int nt = 0; nt < 4; ++nt) {
      float bn = bias[wn * 64 + nt * 16 + lo];
#pragma unroll
      for (int r = 0; r < 4; ++r)
        Y[(m0 + mrow + r) * HD + wn * 64 + nt * 16 + lo] = f2bf((acc[nt][r] + bn) * sc);
    }
  } else {
#pragma unroll
    for (int nt = 0; nt < 4; ++nt) {
      float bn = bias[wn * 64 + nt * 16 + lo];
      unsigned long long pk = 0;
#pragma unroll
      for (int r = 0; r < 4; ++r)
        pk |= (unsigned long long)f2bf(acc[nt][r] + bn) << (16 * r);
      *(unsigned long long*)&vbT[(size_t)(wn * 64 + nt * 16 + lo) * MQ + m0 + mrow] = pk;
    }
  }
}

// ---------------------------------------------------- attention (key-split) ----
// Round 22: r18/r21 structure with XOR-swizzled unpadded LDS (48KB -> 3
// blocks/CU), cheap grow-check, deferred l-reduce. 512 thr / 8 waves;
// waves 0-3 group 1 (cols 0..63), 4-7 group 2 (cols 64..127).
// Swizzle (all arrays, both sides): col_byte ^= ((row&7)<<4).
__global__ __launch_bounds__(512, 4) void attn_split_kernel(
    const unsigned short* __restrict__ qb, const unsigned short* __restrict__ kb,
    const unsigned short* __restrict__ vbT,
    unsigned short* __restrict__ pO1, unsigned short* __restrict__ pO2,
    float2* __restrict__ pstats, int nkeys) {
  __shared__ __align__(16) unsigned short Kls[64 * 128];   // 16 KB swizzled
  __shared__ __align__(16) unsigned short Vt[128 * 64];    // 16 KB swizzled
  __shared__ __align__(16) unsigned short Pls[8][16 * 64]; // 16 KB swizzled

  const int t = threadIdx.x;
  const int w = t >> 6;        // 0..7
  const int g = w >> 2;        // softmax group 0/1
  const int wv = w & 3;        // wave within group -> q-row block
  const int lane = t & 63;
  const int lo = lane & 15;
  const int quad = lane >> 4;
  const int q8 = quad * 8;
  const int xsw = (lo & 7) << 4;  // read-side swizzle for rows nt*16+lo
  const int b = blockIdx.y;
  const int q0 = blockIdx.x * 64;
  const int ksp = blockIdx.z;
  const int kt0 = ksp * nkeys;
  const int ksTot = TK / nkeys;
  const size_t kbase = (size_t)b * TK;

  const size_t qrow = (size_t)b * TQ + q0 + wv * 16 + lo;
  short8 qf[2];
#pragma unroll
  for (int ks = 0; ks < 2; ++ks)
    qf[ks] = *(const short8*)&qb[qrow * HD + g * 64 + ks * 32 + q8];

  floatx4 o[8];
  const floatx4 zz = {0.f, 0.f, 0.f, 0.f};
#pragma unroll
  for (int i = 0; i < 8; ++i) o[i] = zz;
  float m[4], l[4];
#pragma unroll
  for (int r = 0; r < 4; ++r) { m[r] = -1e30f; l[r] = 0.f; }

  for (int kt = kt0; kt < kt0 + nkeys; kt += 64) {
    // cooperative staging, swizzled writes (per-lane, 16B aligned)
#pragma unroll
    for (int i = 0; i < 2; ++i) {
      int c = t + 512 * i;
      int key = c >> 4;
      int kByte = key * 256 + ((((c & 15) * 16)) ^ ((key & 7) << 4));
      *(int4*)((char*)Kls + kByte) =
          *(const int4*)&kb[(kbase + kt + key) * HD + (c & 15) * 8];
      int f = c >> 3;
      int vByte = f * 128 + ((((c & 7) * 16)) ^ ((f & 7) << 4));
      *(int4*)((char*)Vt + vByte) =
          *(const int4*)&vbT[(size_t)f * MQ + kbase + kt + (c & 7) * 8];
    }
    __syncthreads();

    floatx4 s[4];
#pragma unroll
    for (int i = 0; i < 4; ++i) s[i] = zz;
#pragma unroll
    for (int ks = 0; ks < 2; ++ks)
#pragma unroll
      for (int nt = 0; nt < 4; ++nt) {
        int row = nt * 16 + lo;
        short8 kf = *(const short8*)((const char*)Kls + row * 256 +
                                     ((g * 128 + ks * 64 + quad * 16) ^ xsw));
        s[nt] = __builtin_amdgcn_mfma_f32_16x16x32_bf16(qf[ks], kf, s[nt], 0, 0, 0);
      }

    // cheap grow-check: per-lane max only; __any == reduced-max check
    float a4[4];
#pragma unroll
    for (int r = 0; r < 4; ++r)
      a4[r] = fmaxf(fmaxf(s[0][r], s[1][r]), fmaxf(s[2][r], s[3][r]));
    bool grow = false;
#pragma unroll
    for (int r = 0; r < 4; ++r) grow = grow || (a4[r] > m[r] + 5.f);
    if (__any(grow)) {  // rare path: full 16-lane max reduce + rescale
#pragma unroll
      for (int r = 0; r < 4; ++r) {
        float tm = a4[r];
#pragma unroll
        for (int oo = 1; oo < 16; oo <<= 1) tm = fmaxf(tm, __shfl_xor(tm, oo));
        float mn = fmaxf(m[r], tm);
        float al = __expf(m[r] - mn);
        m[r] = mn;
        l[r] *= al;
#pragma unroll
        for (int nt = 0; nt < 8; ++nt) o[nt][r] *= al;
      }
    }
    // P = exp(s-m), swizzled write; l accumulates per-lane partials (deferred)
#pragma unroll
    for (int r = 0; r < 4; ++r) {
      int rr = quad * 4 + r;
      int rsw = (rr & 7) << 4;
      float ls = 0.f;
#pragma unroll
      for (int nt = 0; nt < 4; ++nt) {
        float p = __expf(s[nt][r] - m[r]);
        ls += p;
        *(unsigned short*)((char*)Pls[w] + rr * 128 + (((nt * 16 + lo) * 2) ^ rsw)) =
            f2bf(p);
      }
      l[r] += ls;  // no per-tile reduce
    }

#pragma unroll
    for (int ks = 0; ks < 2; ++ks) {
      int cb = (ks * 64 + quad * 16);
      short8 p8 = *(const short8*)((const char*)Pls[w] + lo * 128 + (cb ^ xsw));
#pragma unroll
      for (int nt = 0; nt < 8; ++nt) {
        short8 vf = *(const short8*)((const char*)Vt + (nt * 16 + lo) * 128 + (cb ^ xsw));
        o[nt] = __builtin_amdgcn_mfma_f32_16x16x32_bf16(p8, vf, o[nt], 0, 0, 0);
      }
    }
    __syncthreads();
  }

  // epilogue: one 16-lane l-reduce (deferred from the loop)
#pragma unroll
  for (int r = 0; r < 4; ++r)
#pragma unroll
    for (int oo = 1; oo < 16; oo <<= 1) l[r] += __shfl_xor(l[r], oo);

  unsigned short* Y = g ? pO2 : pO1;
#pragma unroll
  for (int r = 0; r < 4; ++r) {
    int rowb = q0 + wv * 16 + quad * 4 + r;
    size_t idx = ((size_t)(ksp * 4 + b)) * TQ + rowb;
    if (lo == 0)
      pstats[((size_t)(g * ksTot + ksp) * 4 + b) * TQ + rowb] = make_float2(m[r], l[r]);
#pragma unroll
    for (int nt = 0; nt < 8; ++nt)
      Y[idx * HD + nt * 16 + lo] = f2bf(o[nt][r]);
  }
}

// ---------------------------------------------------------------- combine ----
// pstats layout: [(g*ksn + s)*4 + b)*TQ + row] -> (m, l) per group.
__global__ __launch_bounds__(256) void attn_combine_kernel(
    const unsigned short* __restrict__ pO1, const unsigned short* __restrict__ pO2,
    const float2* __restrict__ pstats, const float* __restrict__ lam_ptr,
    float* __restrict__ out, int ksn) {
  const int t = threadIdx.x;
  const int b = blockIdx.y;
  const int row = blockIdx.x * 16 + (t >> 4);
  const int dg = t & 15;

  float m1s[8], l1s[8], m2s[8], l2s[8];
  float M1 = -1e30f, M2 = -1e30f;
  for (int s = 0; s < ksn; ++s) {
    float2 fa = pstats[((size_t)(s) * 4 + b) * TQ + row];
    float2 fb = pstats[((size_t)(ksn + s) * 4 + b) * TQ + row];
    m1s[s] = fa.x; l1s[s] = fa.y; m2s[s] = fb.x; l2s[s] = fb.y;
    M1 = fmaxf(M1, fa.x); M2 = fmaxf(M2, fb.x);
  }
  float L1 = 0.f, L2 = 0.f, e1[8], e2[8];
  for (int s = 0; s < ksn; ++s) {
    e1[s] = __expf(m1s[s] - M1); e2[s] = __expf(m2s[s] - M2);
    L1 += l1s[s] * e1[s]; L2 += l2s[s] * e2[s];
  }
  float a1[8], a2[8];
#pragma unroll
  for (int j = 0; j < 8; ++j) { a1[j] = 0.f; a2[j] = 0.f; }
  for (int s = 0; s < ksn; ++s) {
    size_t base = (((size_t)(s * 4 + b)) * TQ + row) * HD + dg * 8;
    int4 r1 = *(const int4*)&pO1[base];
    int4 r2 = *(const int4*)&pO2[base];
    const unsigned short* u1 = (const unsigned short*)&r1;
    const unsigned short* u2 = (const unsigned short*)&r2;
#pragma unroll
    for (int j = 0; j < 8; ++j) {
      a1[j] += bf2f(u1[j]) * e1[s];
      a2[j] += bf2f(u2[j]) * e2[s];
    }
  }
  const float i1 = 1.f / L1;
  const float i2 = lam_ptr[0] / L2;
  float4* op = (float4*)&out[((size_t)b * TQ + row) * HD + dg * 8];
  op[0] = make_float4(a1[0] * i1 - a2[0] * i2, a1[1] * i1 - a2[1] * i2,
                      a1[2] * i1 - a2[2] * i2, a1[3] * i1 - a2[3] * i2);
  op[1] = make_float4(a1[4] * i1 - a2[4] * i2, a1[5] * i1 - a2[5] * i2,
                      a1[6] * i1 - a2[6] * i2, a1[7] * i1 - a2[7] * i2);
}

extern "C" void kernel_launch(void* const* d_in, const int* in_sizes, int n_in,
                              void* d_out, int out_size, void* d_ws, size_t ws_size,
                              hipStream_t stream) {
  const float* x    = (const float*)d_in[0];
  const float* enc  = (const float*)d_in[1];
  const float* Wq   = (const float*)d_in[2];
  const float* bq   = (const float*)d_in[3];
  const float* Wk   = (const float*)d_in[4];
  const float* bk   = (const float*)d_in[5];
  const float* Wv   = (const float*)d_in[6];
  const float* bv   = (const float*)d_in[7];
  const float* lq1  = (const float*)d_in[8];
  const float* lk1  = (const float*)d_in[9];
  const float* lq2  = (const float*)d_in[10];
  const float* lk2  = (const float*)d_in[11];
  const float* lini = (const float*)d_in[12];
  float* out = (float*)d_out;

  char* p = (char*)d_ws;
  float* lam = (float*)p;                       p += 256;
  unsigned short* qb  = (unsigned short*)p;     p += (size_t)MQ * HD * 2;
  unsigned short* kb  = (unsigned short*)p;     p += (size_t)MQ * HD * 2;
  unsigned short* vbT = (unsigned short*)p;     p += (size_t)MQ * HD * 2;  // [128][8192]
  unsigned short* WqT = (unsigned short*)p;     p += (size_t)EMB * HD * 2;
  unsigned short* WkT = (unsigned short*)p;     p += (size_t)EMB * HD * 2;
  unsigned short* WvT = (unsigned short*)p;     p += (size_t)EMB * HD * 2;
  const size_t base_need = (size_t)(p - (char*)d_ws);

  // per-KS: stats 2 groups x 4 x TQ x sizeof(float2) (= 4*TQ*16) + pO1/pO2
  const size_t per_ks = (size_t)4 * TQ * 16 + 2ull * 4 * TQ * HD * 2;
  int KS = 8;
  while (KS > 1 && base_need + (size_t)KS * per_ks > ws_size) KS >>= 1;

  float2* pstats = (float2*)p;                  p += (size_t)KS * 4 * TQ * 16;
  unsigned short* pO1 = (unsigned short*)p;     p += (size_t)KS * 4 * TQ * HD * 2;
  unsigned short* pO2 = (unsigned short*)p;

  hipLaunchKernelGGL(cvtWT_kernel, dim3(512, 4), dim3(256), 0, stream,
                     Wq, Wk, Wv, WqT, WkT, WvT, lq1, lk1, lq2, lk2, lini, lam);
  hipLaunchKernelGGL(gemm_proj_kernel, dim3(MQ / 32, 3), dim3(256), 0, stream,
                     x, enc, WqT, WkT, WvT, bq, bk, bv, qb, kb, vbT);
  hipLaunchKernelGGL(attn_split_kernel, dim3(TQ / 64, 4, KS), dim3(512), 0, stream,
                     qb, kb, vbT, pO1, pO2, pstats, TK / KS);
  hipLaunchKernelGGL(attn_combine_kernel, dim3(TQ / 16, 4), dim3(256), 0, stream,
                     pO1, pO2, pstats, lam, out, KS);
}

// Round 13
// 171.940 us; speedup vs baseline: 1.3317x; 1.0338x over previous
//
#include <hip/hip_runtime.h>
#include <hip/hip_bf16.h>

// Problem: B=4, Tq=Tk=2048, E=1024, D=128, d=64. All inputs fp32, output fp32.
// Round 23: cvtWT coalescing on the r22 base (177.8us). r22 post-mortem:
// attn_split dropped below the harness's 41us fill dispatches (first time);
// KS=8 gain ~= combine partial cost (net 0, keep for 3 blocks/CU). Last
// untouched kernel: cvtWT read W[k*HD+n] with consecutive threads walking k
// -> stride-512B gather (~25-50MB HBM for 1.5MB payload). Fix: standard LDS
// 32x32 tile transpose ([32][33] fp32 pad): coalesced float4 reads along n,
// coalesced 8B bf16x4 writes along k. Output bit-identical (same RNE per
// element). attn_split / gemm_proj / combine byte-identical to r22.

#define TQ 2048
#define TK 2048
#define EMB 1024
#define HD 128
#define MQ 8192  // B*Tq rows

typedef __attribute__((ext_vector_type(8))) short short8;   // 8 bf16 = 4 VGPR
typedef __attribute__((ext_vector_type(4))) float floatx4;  // MFMA acc

__device__ __forceinline__ unsigned short f2bf(float f) {  // RNE fp32->bf16
  union { float f; unsigned u; } v; v.f = f;
  unsigned r = v.u + 0x7fffu + ((v.u >> 16) & 1u);
  return (unsigned short)(r >> 16);
}
__device__ __forceinline__ float bf2f(unsigned short s) {
  union { unsigned u; float f; } v; v.u = ((unsigned)s) << 16;
  return v.f;
}

typedef const __attribute__((address_space(1))) unsigned int guint;
typedef __attribute__((address_space(3))) unsigned int luint;
__device__ __forceinline__ void gl16(const void* g, void* l) {
  __builtin_amdgcn_global_load_lds((guint*)g, (luint*)l, 16, 0, 0);
}

// ------------------------------------- weight convert+transpose (+ lambda) ----
// Round 23: LDS 32x32 tile transpose. grid (128, 4): y<3 -> matrix y, tile
// x (kt = x>>2 in [0,32), nt = x&3 in [0,4)); y==3,x==0 -> lambda.
// Reads coalesced along n (float4), writes coalesced along k (bf16x4 = 8B).
__global__ __launch_bounds__(256) void cvtWT_kernel(
    const float* __restrict__ Wq, const float* __restrict__ Wk,
    const float* __restrict__ Wv, unsigned short* __restrict__ WqT,
    unsigned short* __restrict__ WkT, unsigned short* __restrict__ WvT,
    const float* __restrict__ lq1, const float* __restrict__ lk1,
    const float* __restrict__ lq2, const float* __restrict__ lk2,
    const float* __restrict__ linit, float* __restrict__ lam_out) {
  const int g = blockIdx.y;
  if (g == 3) {  // lambda: one block, first wave
    if (blockIdx.x == 0 && threadIdx.x < 64) {
      int j = threadIdx.x;
      float s1 = lq1[j] * lk1[j] + lq1[j + 64] * lk1[j + 64];
      float s2 = lq2[j] * lk2[j] + lq2[j + 64] * lk2[j + 64];
      for (int off = 1; off < 64; off <<= 1) {
        s1 += __shfl_xor(s1, off);
        s2 += __shfl_xor(s2, off);
      }
      if (j == 0) lam_out[0] = __expf(s1) - __expf(s2) + linit[0];
    }
    return;
  }
  __shared__ float tile[32][33];  // +1 pad: transposed column reads conflict-free
  const float* W = (g == 0) ? Wq : (g == 1) ? Wk : Wv;
  unsigned short* WT = (g == 0) ? WqT : (g == 1) ? WkT : WvT;
  const int kt = blockIdx.x >> 2, nt = blockIdx.x & 3;
  const int k0 = kt * 32, n0 = nt * 32;
  const int t = threadIdx.x;
  const int r = t >> 3, c4 = (t & 7) * 4;

  // coalesced read: row k0+r, n-cols n0+c4..+3 (8 thr x 16B = 128B/row)
  float4 v = *(const float4*)&W[(size_t)(k0 + r) * HD + n0 + c4];
  tile[r][c4] = v.x; tile[r][c4 + 1] = v.y;
  tile[r][c4 + 2] = v.z; tile[r][c4 + 3] = v.w;
  __syncthreads();

  // coalesced write: WT row n0+r, k-cols k0+c4..+3 (8B per thread)
  unsigned long long pk;
  pk  = (unsigned long long)f2bf(tile[c4 + 0][r]);
  pk |= (unsigned long long)f2bf(tile[c4 + 1][r]) << 16;
  pk |= (unsigned long long)f2bf(tile[c4 + 2][r]) << 32;
  pk |= (unsigned long long)f2bf(tile[c4 + 3][r]) << 48;
  *(unsigned long long*)&WT[(size_t)(n0 + r) * EMB + k0 + c4] = pk;
}

// -------------------------------------------------------- MFMA projections ----
// grid (MQ/32, 3), 256 thr (4 waves). wave w: wm=w&1 -> rows 16wm..+16,
// wn=w>>1 -> cols 64wn..+64. Per K-step (BK=64): A fp32 32x64 (8KB, 8 chunks)
// + B^T bf16 128x64 (16KB, 16 chunks) staged via global_load_lds dwordx4,
// double-buffered; 8 MFMA/wave. g=0: qb*(0.125); g=1: kb; g=2: vbT^T.
__global__ __launch_bounds__(256) void gemm_proj_kernel(
    const float* __restrict__ x, const float* __restrict__ enc,
    const unsigned short* __restrict__ WqT, const unsigned short* __restrict__ WkT,
    const unsigned short* __restrict__ WvT,
    const float* __restrict__ bq, const float* __restrict__ bk,
    const float* __restrict__ bv,
    unsigned short* __restrict__ qb, unsigned short* __restrict__ kb,
    unsigned short* __restrict__ vbT) {
  __shared__ __align__(16) float Ab[2][32 * 64];             // 16 KB, linear (no pad)
  __shared__ __align__(16) unsigned short Bb[2][128 * 64];   // 32 KB, linear (no pad)
  const int t = threadIdx.x;
  const int w = t >> 6, lane = t & 63;
  const int lo = lane & 15, quad = lane >> 4;
  const int wm = w & 1, wn = w >> 1;
  const int g = blockIdx.y;
  const size_t m0 = (size_t)blockIdx.x * 32;
  const float* A = (g == 0) ? x : enc;
  const unsigned short* BT = (g == 0) ? WqT : (g == 1) ? WkT : WvT;
  const float* bias = (g == 0) ? bq : (g == 1) ? bk : bv;

  // Per-lane staging sources, pre-swizzled so linear LDS + swizzled ds_read
  // reconstructs the original element (involution: col_byte ^= ((row&7)<<4)).
  // A: 8 chunks of 1KB (4 rows x 256B); wave w owns chunks 2w, 2w+1.
  const float* gA[2];
  int ldsAoff[2];
#pragma unroll
  for (int j = 0; j < 2; ++j) {
    int c = 2 * w + j;
    int row = 4 * c + (lane >> 4);
    int colb = ((lane & 15) * 16) ^ ((row & 7) << 4);
    gA[j] = A + (m0 + row) * EMB + (colb >> 2);
    ldsAoff[j] = c * 1024;
  }
  // B: 16 chunks of 1KB (8 rows x 128B); wave w owns chunks 4w..4w+3.
  const unsigned short* gB[4];
  int ldsBoff[4];
#pragma unroll
  for (int j = 0; j < 4; ++j) {
    int c = 4 * w + j;
    int row = 8 * c + (lane >> 3);
    int colb = ((lane & 7) * 16) ^ ((row & 7) << 4);
    gB[j] = BT + (size_t)row * EMB + (colb >> 1);
    ldsBoff[j] = c * 1024;
  }

  floatx4 acc[4];
  const floatx4 zz = {0.f, 0.f, 0.f, 0.f};
#pragma unroll
  for (int i = 0; i < 4; ++i) acc[i] = zz;

  const int xr = (lo & 7) << 4;

  auto stage = [&](int kt, int bsel) {
#pragma unroll
    for (int j = 0; j < 2; ++j) gl16(gA[j] + kt, (char*)&Ab[bsel][0] + ldsAoff[j]);
#pragma unroll
    for (int j = 0; j < 4; ++j) gl16(gB[j] + kt, (char*)&Bb[bsel][0] + ldsBoff[j]);
  };

  auto compute = [&](int bsel) {
    const char* Arow = (const char*)&Ab[bsel][(16 * wm + lo) * 64];
    const char* Bbase = (const char*)&Bb[bsel][0];
#pragma unroll
    for (int ks = 0; ks < 2; ++ks) {
      int a0 = (ks * 128 + quad * 32) ^ xr;
      float4 fa = *(const float4*)(Arow + a0);         // orig cols ks*32+q8 .. +3
      float4 fb = *(const float4*)(Arow + (a0 ^ 16));  // orig cols ks*32+q8+4 .. +7
      short8 af;
      af[0] = (short)f2bf(fa.x); af[1] = (short)f2bf(fa.y);
      af[2] = (short)f2bf(fa.z); af[3] = (short)f2bf(fa.w);
      af[4] = (short)f2bf(fb.x); af[5] = (short)f2bf(fb.y);
      af[6] = (short)f2bf(fb.z); af[7] = (short)f2bf(fb.w);
      int b0 = (ks * 64 + quad * 16) ^ xr;
#pragma unroll
      for (int nt = 0; nt < 4; ++nt) {
        int row = wn * 64 + nt * 16 + lo;
        short8 bfr = *(const short8*)(Bbase + row * 128 + b0);
        acc[nt] = __builtin_amdgcn_mfma_f32_16x16x32_bf16(af, bfr, acc[nt], 0, 0, 0);
      }
    }
  };

  // prologue: stage K-tile 0 into buf0 (syncthreads drains vmcnt+lgkmcnt)
  stage(0, 0);
  __syncthreads();

  // 2-phase pipeline, unrolled 2-deep -> static buffer indices
  for (int kt = 0; kt < EMB; kt += 128) {
    stage(kt + 64, 1);          // prefetch next tile (kt+64 <= 960, always valid)
    compute(0);                 // consume tile kt
    __syncthreads();            // drains: buf1 loads done, buf0 reads done
    if (kt + 128 < EMB) stage(kt + 128, 0);
    compute(1);                 // consume tile kt+64
    __syncthreads();
  }

  // epilogue: rows m0+16wm+quad*4+r, cols 64wn+nt*16+lo
  const int mrow = 16 * wm + quad * 4;
  if (g < 2) {
    unsigned short* Y = (g == 0) ? qb : kb;
    const float sc = (g == 0) ? 0.125f : 1.0f;
#pragma unroll
    for (int nt = 0; nt < 4; ++nt) {
      float bn = bias[wn * 64 + nt * 16 + lo];
#pragma unroll
      for (int r = 0; r < 4; ++r)
        Y[(m0 + mrow + r) * HD + wn * 64 + nt * 16 + lo] = f2bf((acc[nt][r] + bn) * sc);
    }
  } else {
#pragma unroll
    for (int nt = 0; nt < 4; ++nt) {
      float bn = bias[wn * 64 + nt * 16 + lo];
      unsigned long long pk = 0;
#pragma unroll
      for (int r = 0; r < 4; ++r)
        pk |= (unsigned long long)f2bf(acc[nt][r] + bn) << (16 * r);
      *(unsigned long long*)&vbT[(size_t)(wn * 64 + nt * 16 + lo) * MQ + m0 + mrow] = pk;
    }
  }
}

// ---------------------------------------------------- attention (key-split) ----
// r22 kernel verbatim. XOR-swizzled unpadded LDS (48KB -> 3 blocks/CU),
// cheap grow-check, deferred l-reduce. 512 thr / 8 waves; waves 0-3 group 1
// (cols 0..63), 4-7 group 2 (cols 64..127). Swizzle: col_byte ^= ((row&7)<<4).
__global__ __launch_bounds__(512, 4) void attn_split_kernel(
    const unsigned short* __restrict__ qb, const unsigned short* __restrict__ kb,
    const unsigned short* __restrict__ vbT,
    unsigned short* __restrict__ pO1, unsigned short* __restrict__ pO2,
    float2* __restrict__ pstats, int nkeys) {
  __shared__ __align__(16) unsigned short Kls[64 * 128];   // 16 KB swizzled
  __shared__ __align__(16) unsigned short Vt[128 * 64];    // 16 KB swizzled
  __shared__ __align__(16) unsigned short Pls[8][16 * 64]; // 16 KB swizzled

  const int t = threadIdx.x;
  const int w = t >> 6;        // 0..7
  const int g = w >> 2;        // softmax group 0/1
  const int wv = w & 3;        // wave within group -> q-row block
  const int lane = t & 63;
  const int lo = lane & 15;
  const int quad = lane >> 4;
  const int q8 = quad * 8;
  const int xsw = (lo & 7) << 4;  // read-side swizzle for rows nt*16+lo
  const int b = blockIdx.y;
  const int q0 = blockIdx.x * 64;
  const int ksp = blockIdx.z;
  const int kt0 = ksp * nkeys;
  const int ksTot = TK / nkeys;
  const size_t kbase = (size_t)b * TK;

  const size_t qrow = (size_t)b * TQ + q0 + wv * 16 + lo;
  short8 qf[2];
#pragma unroll
  for (int ks = 0; ks < 2; ++ks)
    qf[ks] = *(const short8*)&qb[qrow * HD + g * 64 + ks * 32 + q8];

  floatx4 o[8];
  const floatx4 zz = {0.f, 0.f, 0.f, 0.f};
#pragma unroll
  for (int i = 0; i < 8; ++i) o[i] = zz;
  float m[4], l[4];
#pragma unroll
  for (int r = 0; r < 4; ++r) { m[r] = -1e30f; l[r] = 0.f; }

  for (int kt = kt0; kt < kt0 + nkeys; kt += 64) {
    // cooperative staging, swizzled writes (per-lane, 16B aligned)
#pragma unroll
    for (int i = 0; i < 2; ++i) {
      int c = t + 512 * i;
      int key = c >> 4;
      int kByte = key * 256 + ((((c & 15) * 16)) ^ ((key & 7) << 4));
      *(int4*)((char*)Kls + kByte) =
          *(const int4*)&kb[(kbase + kt + key) * HD + (c & 15) * 8];
      int f = c >> 3;
      int vByte = f * 128 + ((((c & 7) * 16)) ^ ((f & 7) << 4));
      *(int4*)((char*)Vt + vByte) =
          *(const int4*)&vbT[(size_t)f * MQ + kbase + kt + (c & 7) * 8];
    }
    __syncthreads();

    floatx4 s[4];
#pragma unroll
    for (int i = 0; i < 4; ++i) s[i] = zz;
#pragma unroll
    for (int ks = 0; ks < 2; ++ks)
#pragma unroll
      for (int nt = 0; nt < 4; ++nt) {
        int row = nt * 16 + lo;
        short8 kf = *(const short8*)((const char*)Kls + row * 256 +
                                     ((g * 128 + ks * 64 + quad * 16) ^ xsw));
        s[nt] = __builtin_amdgcn_mfma_f32_16x16x32_bf16(qf[ks], kf, s[nt], 0, 0, 0);
      }

    // cheap grow-check: per-lane max only; __any == reduced-max check
    float a4[4];
#pragma unroll
    for (int r = 0; r < 4; ++r)
      a4[r] = fmaxf(fmaxf(s[0][r], s[1][r]), fmaxf(s[2][r], s[3][r]));
    bool grow = false;
#pragma unroll
    for (int r = 0; r < 4; ++r) grow = grow || (a4[r] > m[r] + 5.f);
    if (__any(grow)) {  // rare path: full 16-lane max reduce + rescale
#pragma unroll
      for (int r = 0; r < 4; ++r) {
        float tm = a4[r];
#pragma unroll
        for (int oo = 1; oo < 16; oo <<= 1) tm = fmaxf(tm, __shfl_xor(tm, oo));
        float mn = fmaxf(m[r], tm);
        float al = __expf(m[r] - mn);
        m[r] = mn;
        l[r] *= al;
#pragma unroll
        for (int nt = 0; nt < 8; ++nt) o[nt][r] *= al;
      }
    }
    // P = exp(s-m), swizzled write; l accumulates per-lane partials (deferred)
#pragma unroll
    for (int r = 0; r < 4; ++r) {
      int rr = quad * 4 + r;
      int rsw = (rr & 7) << 4;
      float ls = 0.f;
#pragma unroll
      for (int nt = 0; nt < 4; ++nt) {
        float p = __expf(s[nt][r] - m[r]);
        ls += p;
        *(unsigned short*)((char*)Pls[w] + rr * 128 + (((nt * 16 + lo) * 2) ^ rsw)) =
            f2bf(p);
      }
      l[r] += ls;  // no per-tile reduce
    }

#pragma unroll
    for (int ks = 0; ks < 2; ++ks) {
      int cb = (ks * 64 + quad * 16);
      short8 p8 = *(const short8*)((const char*)Pls[w] + lo * 128 + (cb ^ xsw));
#pragma unroll
      for (int nt = 0; nt < 8; ++nt) {
        short8 vf = *(const short8*)((const char*)Vt + (nt * 16 + lo) * 128 + (cb ^ xsw));
        o[nt] = __builtin_amdgcn_mfma_f32_16x16x32_bf16(p8, vf, o[nt], 0, 0, 0);
      }
    }
    __syncthreads();
  }

  // epilogue: one 16-lane l-reduce (deferred from the loop)
#pragma unroll
  for (int r = 0; r < 4; ++r)
#pragma unroll
    for (int oo = 1; oo < 16; oo <<= 1) l[r] += __shfl_xor(l[r], oo);

  unsigned short* Y = g ? pO2 : pO1;
#pragma unroll
  for (int r = 0; r < 4; ++r) {
    int rowb = q0 + wv * 16 + quad * 4 + r;
    size_t idx = ((size_t)(ksp * 4 + b)) * TQ + rowb;
    if (lo == 0)
      pstats[((size_t)(g * ksTot + ksp) * 4 + b) * TQ + rowb] = make_float2(m[r], l[r]);
#pragma unroll
    for (int nt = 0; nt < 8; ++nt)
      Y[idx * HD + nt * 16 + lo] = f2bf(o[nt][r]);
  }
}

// ---------------------------------------------------------------- combine ----
// pstats layout: [(g*ksn + s)*4 + b)*TQ + row] -> (m, l) per group.
__global__ __launch_bounds__(256) void attn_combine_kernel(
    const unsigned short* __restrict__ pO1, const unsigned short* __restrict__ pO2,
    const float2* __restrict__ pstats, const float* __restrict__ lam_ptr,
    float* __restrict__ out, int ksn) {
  const int t = threadIdx.x;
  const int b = blockIdx.y;
  const int row = blockIdx.x * 16 + (t >> 4);
  const int dg = t & 15;

  float m1s[8], l1s[8], m2s[8], l2s[8];
  float M1 = -1e30f, M2 = -1e30f;
  for (int s = 0; s < ksn; ++s) {
    float2 fa = pstats[((size_t)(s) * 4 + b) * TQ + row];
    float2 fb = pstats[((size_t)(ksn + s) * 4 + b) * TQ + row];
    m1s[s] = fa.x; l1s[s] = fa.y; m2s[s] = fb.x; l2s[s] = fb.y;
    M1 = fmaxf(M1, fa.x); M2 = fmaxf(M2, fb.x);
  }
  float L1 = 0.f, L2 = 0.f, e1[8], e2[8];
  for (int s = 0; s < ksn; ++s) {
    e1[s] = __expf(m1s[s] - M1); e2[s] = __expf(m2s[s] - M2);
    L1 += l1s[s] * e1[s]; L2 += l2s[s] * e2[s];
  }
  float a1[8], a2[8];
#pragma unroll
  for (int j = 0; j < 8; ++j) { a1[j] = 0.f; a2[j] = 0.f; }
  for (int s = 0; s < ksn; ++s) {
    size_t base = (((size_t)(s * 4 + b)) * TQ + row) * HD + dg * 8;
    int4 r1 = *(const int4*)&pO1[base];
    int4 r2 = *(const int4*)&pO2[base];
    const unsigned short* u1 = (const unsigned short*)&r1;
    const unsigned short* u2 = (const unsigned short*)&r2;
#pragma unroll
    for (int j = 0; j < 8; ++j) {
      a1[j] += bf2f(u1[j]) * e1[s];
      a2[j] += bf2f(u2[j]) * e2[s];
    }
  }
  const float i1 = 1.f / L1;
  const float i2 = lam_ptr[0] / L2;
  float4* op = (float4*)&out[((size_t)b * TQ + row) * HD + dg * 8];
  op[0] = make_float4(a1[0] * i1 - a2[0] * i2, a1[1] * i1 - a2[1] * i2,
                      a1[2] * i1 - a2[2] * i2, a1[3] * i1 - a2[3] * i2);
  op[1] = make_float4(a1[4] * i1 - a2[4] * i2, a1[5] * i1 - a2[5] * i2,
                      a1[6] * i1 - a2[6] * i2, a1[7] * i1 - a2[7] * i2);
}

extern "C" void kernel_launch(void* const* d_in, const int* in_sizes, int n_in,
                              void* d_out, int out_size, void* d_ws, size_t ws_size,
                              hipStream_t stream) {
  const float* x    = (const float*)d_in[0];
  const float* enc  = (const float*)d_in[1];
  const float* Wq   = (const float*)d_in[2];
  const float* bq   = (const float*)d_in[3];
  const float* Wk   = (const float*)d_in[4];
  const float* bk   = (const float*)d_in[5];
  const float* Wv   = (const float*)d_in[6];
  const float* bv   = (const float*)d_in[7];
  const float* lq1  = (const float*)d_in[8];
  const float* lk1  = (const float*)d_in[9];
  const float* lq2  = (const float*)d_in[10];
  const float* lk2  = (const float*)d_in[11];
  const float* lini = (const float*)d_in[12];
  float* out = (float*)d_out;

  char* p = (char*)d_ws;
  float* lam = (float*)p;                       p += 256;
  unsigned short* qb  = (unsigned short*)p;     p += (size_t)MQ * HD * 2;
  unsigned short* kb  = (unsigned short*)p;     p += (size_t)MQ * HD * 2;
  unsigned short* vbT = (unsigned short*)p;     p += (size_t)MQ * HD * 2;  // [128][8192]
  unsigned short* WqT = (unsigned short*)p;     p += (size_t)EMB * HD * 2;
  unsigned short* WkT = (unsigned short*)p;     p += (size_t)EMB * HD * 2;
  unsigned short* WvT = (unsigned short*)p;     p += (size_t)EMB * HD * 2;
  const size_t base_need = (size_t)(p - (char*)d_ws);

  // per-KS: stats 2 groups x 4 x TQ x sizeof(float2) (= 4*TQ*16) + pO1/pO2
  const size_t per_ks = (size_t)4 * TQ * 16 + 2ull * 4 * TQ * HD * 2;
  int KS = 8;
  while (KS > 1 && base_need + (size_t)KS * per_ks > ws_size) KS >>= 1;

  float2* pstats = (float2*)p;                  p += (size_t)KS * 4 * TQ * 16;
  unsigned short* pO1 = (unsigned short*)p;     p += (size_t)KS * 4 * TQ * HD * 2;
  unsigned short* pO2 = (unsigned short*)p;

  hipLaunchKernelGGL(cvtWT_kernel, dim3(128, 4), dim3(256), 0, stream,
                     Wq, Wk, Wv, WqT, WkT, WvT, lq1, lk1, lq2, lk2, lini, lam);
  hipLaunchKernelGGL(gemm_proj_kernel, dim3(MQ / 32, 3), dim3(256), 0, stream,
                     x, enc, WqT, WkT, WvT, bq, bk, bv, qb, kb, vbT);
  hipLaunchKernelGGL(attn_split_kernel, dim3(TQ / 64, 4, KS), dim3(512), 0, stream,
                     qb, kb, vbT, pO1, pO2, pstats, TK / KS);
  hipLaunchKernelGGL(attn_combine_kernel, dim3(TQ / 16, 4), dim3(256), 0, stream,
                     pO1, pO2, pstats, lam, out, KS);
}